// Round 8
// baseline (670.757 us; speedup 1.0000x reference)
//
#include <hip/hip_runtime.h>
#include <math.h>

constexpr int Nn = 50000;
constexpr int Ee = 800000;
constexpr int NBLK = (Nn + 255) / 256;  // 196

typedef __attribute__((ext_vector_type(8))) short short8;
typedef __attribute__((ext_vector_type(4))) float f32x4;

__device__ inline unsigned short f2bf_rtn(float f) {
  union { float f; unsigned u; } v; v.f = f;
  unsigned r = v.u + 0x7FFFu + ((v.u >> 16) & 1u);
  return (unsigned short)(r >> 16);
}
__device__ inline float bf2f(unsigned short h) {
  union { unsigned u; float f; } v; v.u = ((unsigned)h) << 16;
  return v.f;
}

// ---------------- CSR build ----------------
__global__ void k_count(const int* __restrict__ dst, int* __restrict__ cnt) {
  int e = blockIdx.x * 256 + threadIdx.x;
  if (e < Ee) atomicAdd(&cnt[dst[e]], 1);
}

__global__ __launch_bounds__(256) void k_bsum(const int* __restrict__ cnt, int* __restrict__ bsum) {
  __shared__ int sh[256];
  int i = blockIdx.x * 256 + threadIdx.x;
  int v = (i < Nn) ? cnt[i] : 0;
  sh[threadIdx.x] = v;
  __syncthreads();
  #pragma unroll
  for (int off = 128; off > 0; off >>= 1) {
    if (threadIdx.x < off) sh[threadIdx.x] += sh[threadIdx.x + off];
    __syncthreads();
  }
  if (threadIdx.x == 0) bsum[blockIdx.x] = sh[0];
}

__global__ __launch_bounds__(256) void k_bscan(const int* __restrict__ bsum,
                                               int* __restrict__ bbase, int* __restrict__ offs) {
  __shared__ int sh[256];
  int t = threadIdx.x;
  int v = (t < NBLK) ? bsum[t] : 0;
  sh[t] = v;
  __syncthreads();
  #pragma unroll
  for (int off = 1; off < 256; off <<= 1) {
    int u = (t >= off) ? sh[t - off] : 0;
    __syncthreads();
    sh[t] += u;
    __syncthreads();
  }
  if (t < NBLK) bbase[t] = sh[t] - v;
  if (t == 0) offs[Nn] = Ee;
}

__global__ __launch_bounds__(256) void k_offsets(const int* __restrict__ cnt,
                                                 const int* __restrict__ bbase,
                                                 int* __restrict__ offs, float* __restrict__ dinv) {
  __shared__ int sh[256];
  int i = blockIdx.x * 256 + threadIdx.x;
  int t = threadIdx.x;
  int v = (i < Nn) ? cnt[i] : 0;
  sh[t] = v;
  __syncthreads();
  #pragma unroll
  for (int off = 1; off < 256; off <<= 1) {
    int u = (t >= off) ? sh[t - off] : 0;
    __syncthreads();
    sh[t] += u;
    __syncthreads();
  }
  if (i < Nn) {
    offs[i] = bbase[blockIdx.x] + sh[t] - v;
    dinv[i] = rsqrtf(fmaxf((float)v, 1e-12f));
  }
}

__global__ void k_scatter(const int* __restrict__ src, const int* __restrict__ dst,
                          const int* __restrict__ offs, int* __restrict__ cur,
                          int* __restrict__ csr) {
  int e = blockIdx.x * 256 + threadIdx.x;
  if (e < Ee) {
    int d = dst[e];
    int p = offs[d] + atomicAdd(&cur[d], 1);
    csr[p] = src[e];
  }
}

// ---------------- column stats (64-wide, ddof=1); statsx also emits Xs = feat*dinv ----------------
template <bool EMITXS>
__global__ __launch_bounds__(256) void k_stats(const float* __restrict__ X, double* __restrict__ acc,
                                               const float* __restrict__ dinv, float* __restrict__ Xs) {
  int col = threadIdx.x & 63, rs_ = threadIdx.x >> 6;
  int row0 = blockIdx.x * 256;
  int rend = min(row0 + 256, Nn);
  double s = 0.0, ss = 0.0;
  for (int r = row0 + rs_; r < rend; r += 4) {
    float v = X[(size_t)r * 64 + col];
    if (EMITXS) Xs[(size_t)r * 64 + col] = v * dinv[r];
    s += v; ss += (double)v * v;
  }
  __shared__ double sh[512];
  sh[threadIdx.x] = s; sh[256 + threadIdx.x] = ss;
  __syncthreads();
  if (rs_ == 0) {
    s = sh[col] + sh[col + 64] + sh[col + 128] + sh[col + 192];
    ss = sh[256 + col] + sh[256 + col + 64] + sh[256 + col + 128] + sh[256 + col + 192];
    atomicAdd(&acc[col], s);
    atomicAdd(&acc[64 + col], ss);
  }
}

// inline stats finalization helper (compute mean + 1/std into shared arrays, threads 0..63)
__device__ inline void stats_final_sh(const double* acc, float* smean, float* srstd, int t) {
  if (t < 64) {
    double s = acc[t], ss = acc[64 + t];
    double m = s / (double)Nn;
    double var = (ss - s * s / (double)Nn) / (double)(Nn - 1);
    double sd = sqrt(var > 0.0 ? var : 0.0);
    if (sd < 1e-8) sd = 1e-8;
    smean[t] = (float)m;
    srstd[t] = (float)(1.0 / sd);
  }
}

// ---------------- local Dirichlet energy ----------------
__global__ __launch_bounds__(256) void k_energy(const float* __restrict__ Xs,
                                                const int* __restrict__ cnt,
                                                const int* __restrict__ offs,
                                                const int* __restrict__ csr,
                                                float* __restrict__ R) {
  int wid = threadIdx.x >> 6, lane = threadIdx.x & 63;
  int node = blockIdx.x * 4 + wid;
  if (node >= Nn) return;
  int q4 = lane >> 4;
  int cg = (lane & 15) * 4;
  float4 xi = *(const float4*)(Xs + (size_t)node * 64 + cg);
  float num[4] = {0.f, 0.f, 0.f, 0.f}, den[4] = {0.f, 0.f, 0.f, 0.f};
  int j0 = offs[node], j1 = offs[node + 1];
  for (int j = j0; j < j1; j += 4) {
    int e = j + q4;
    if (e < j1) {
      float4 xs = *(const float4*)(Xs + (size_t)csr[e] * 64 + cg);
      float d0 = xi.x - xs.x, d1 = xi.y - xs.y, d2 = xi.z - xs.z, d3 = xi.w - xs.w;
      num[0] += d0 * d0; num[1] += d1 * d1; num[2] += d2 * d2; num[3] += d3 * d3;
      den[0] += xs.x * xs.x; den[1] += xs.y * xs.y; den[2] += xs.z * xs.z; den[3] += xs.w * xs.w;
    }
  }
  #pragma unroll
  for (int c = 0; c < 4; c++) {
    num[c] += __shfl_xor(num[c], 32); num[c] += __shfl_xor(num[c], 16);
    den[c] += __shfl_xor(den[c], 32); den[c] += __shfl_xor(den[c], 16);
  }
  if (q4 == 0) {
    float degf = (float)cnt[node];
    float4 o;
    o.x = num[0] / (den[0] + degf * xi.x * xi.x + 1e-8f);
    o.y = num[1] / (den[1] + degf * xi.y * xi.y + 1e-8f);
    o.z = num[2] / (den[2] + degf * xi.z * xi.z + 1e-8f);
    o.w = num[3] / (den[3] + degf * xi.w * xi.w + 1e-8f);
    *(float4*)(R + (size_t)node * 64 + cg) = o;
  }
}

// ---------------- gate MLP + Z (in-place R -> Z, fp32); stats finalized inline ----------------
__global__ __launch_bounds__(256) void k_gate(const float* __restrict__ feat,
                                              const double* __restrict__ accF,
                                              const double* __restrict__ accR,
                                              const float* __restrict__ w1, const float* __restrict__ b1,
                                              const float* __restrict__ w2, const float* __restrict__ b2,
                                              float* __restrict__ RZ) {
  __shared__ float sw1[1024], sw2[1024], sb1[16], sb2[64], sfm[64], sfr[64], srm[64], srr[64];
  for (int i = threadIdx.x; i < 1024; i += 256) { sw1[i] = w1[i]; sw2[i] = w2[i]; }
  if (threadIdx.x < 16) sb1[threadIdx.x] = b1[threadIdx.x];
  if (threadIdx.x < 64) sb2[threadIdx.x] = b2[threadIdx.x];
  stats_final_sh(accF, sfm, sfr, threadIdx.x);
  stats_final_sh(accR, srm, srr, threadIdx.x);
  __syncthreads();
  int node = blockIdx.x * 256 + threadIdx.x;
  if (node >= Nn) return;
  float xn[64];
  const float4* fx = (const float4*)(feat + (size_t)node * 64);
  for (int q = 0; q < 16; q++) {
    float4 v = fx[q];
    xn[q * 4 + 0] = (v.x - sfm[q * 4 + 0]) * sfr[q * 4 + 0];
    xn[q * 4 + 1] = (v.y - sfm[q * 4 + 1]) * sfr[q * 4 + 1];
    xn[q * 4 + 2] = (v.z - sfm[q * 4 + 2]) * sfr[q * 4 + 2];
    xn[q * 4 + 3] = (v.w - sfm[q * 4 + 3]) * sfr[q * 4 + 3];
  }
  float hid[16];
  #pragma unroll
  for (int h = 0; h < 16; h++) {
    float a = sb1[h];
    #pragma unroll
    for (int k = 0; k < 64; k++) a += xn[k] * sw1[k * 16 + h];
    hid[h] = fmaxf(a, 0.f);
  }
  float4* row = (float4*)(RZ + (size_t)node * 64);
  for (int q = 0; q < 16; q++) {
    float4 rv = row[q];
    float Rv[4] = {rv.x, rv.y, rv.z, rv.w};
    float zo[4];
    #pragma unroll
    for (int j = 0; j < 4; j++) {
      int o = q * 4 + j;
      float a = sb2[o];
      #pragma unroll
      for (int h = 0; h < 16; h++) a += hid[h] * sw2[h * 64 + o];
      float g = 1.f / (1.f + expf(-a));
      float Rn = (Rv[j] - srm[o]) * srr[o];
      float Rf = (2.f - Rv[j] - srm[o]) * srr[o];
      zo[j] = g * Rn + (1.f - g) * Rf;
    }
    row[q] = make_float4(zo[0], zo[1], zo[2], zo[3]);
  }
}

// ---------------- attn MLP + h0 = en*attn (Z fp32 -> H0 bf16, coalesced store) ----------------
__global__ __launch_bounds__(256) void k_attn(const double* __restrict__ accZ,
                                              const float* __restrict__ w1, const float* __restrict__ b1,
                                              const float* __restrict__ w2, const float* __restrict__ b2,
                                              const float* __restrict__ Zf,
                                              unsigned short* __restrict__ Hh) {
  __shared__ float sw1[1024], sw2[1024], sb1[16], sb2[64], szm[64], szr[64];
  __shared__ unsigned short sout[256][72];
  for (int i = threadIdx.x; i < 1024; i += 256) { sw1[i] = w1[i]; sw2[i] = w2[i]; }
  if (threadIdx.x < 16) sb1[threadIdx.x] = b1[threadIdx.x];
  if (threadIdx.x < 64) sb2[threadIdx.x] = b2[threadIdx.x];
  stats_final_sh(accZ, szm, szr, threadIdx.x);
  __syncthreads();
  int node0 = blockIdx.x * 256;
  int node = node0 + threadIdx.x;
  if (node < Nn) {
    float en[64];
    const float4* row = (const float4*)(Zf + (size_t)node * 64);
    for (int q = 0; q < 16; q++) {
      float4 v = row[q];
      en[q * 4 + 0] = (v.x - szm[q * 4 + 0]) * szr[q * 4 + 0];
      en[q * 4 + 1] = (v.y - szm[q * 4 + 1]) * szr[q * 4 + 1];
      en[q * 4 + 2] = (v.z - szm[q * 4 + 2]) * szr[q * 4 + 2];
      en[q * 4 + 3] = (v.w - szm[q * 4 + 3]) * szr[q * 4 + 3];
    }
    float hid[16];
    #pragma unroll
    for (int h = 0; h < 16; h++) {
      float a = sb1[h];
      #pragma unroll
      for (int k = 0; k < 64; k++) a += en[k] * sw1[k * 16 + h];
      hid[h] = fmaxf(a, 0.f);
    }
    for (int q = 0; q < 16; q++) {
      #pragma unroll
      for (int j = 0; j < 4; j++) {
        int o = q * 4 + j;
        float a = sb2[o];
        #pragma unroll
        for (int h = 0; h < 16; h++) a += hid[h] * sw2[h * 64 + o];
        float att = 1.f / (1.f + expf(-a));
        sout[threadIdx.x][o] = f2bf_rtn(en[o] * att);
      }
    }
  }
  __syncthreads();
  int nval = (min(Nn - node0, 256)) * 64;
  for (int base = 0; base < 16384; base += 2048) {
    int i = base + threadIdx.x * 8;
    if (i < nval) {
      int r = i >> 6, c = i & 63;
      *(short8*)(Hh + (size_t)node0 * 64 + i) = *(const short8*)&sout[r][c];
    }
  }
}

// ---------------- neighbor-mean pulls ----------------
__global__ __launch_bounds__(256) void k_pull64b(const unsigned short* __restrict__ Xh,
                                                 const int* __restrict__ cnt,
                                                 const int* __restrict__ offs,
                                                 const int* __restrict__ csr,
                                                 unsigned short* __restrict__ Oh) {
  int wid = threadIdx.x >> 6, lane = threadIdx.x & 63;
  int node = blockIdx.x * 4 + wid;
  if (node >= Nn) return;
  int o8 = lane >> 3;
  int cg = (lane & 7) * 8;
  float s[8] = {0.f, 0.f, 0.f, 0.f, 0.f, 0.f, 0.f, 0.f};
  int j0 = offs[node], j1 = offs[node + 1];
  for (int j = j0; j < j1; j += 8) {
    int e = j + o8;
    if (e < j1) {
      short8 v = *(const short8*)(Xh + (size_t)csr[e] * 64 + cg);
      #pragma unroll
      for (int q = 0; q < 8; q++) s[q] += bf2f((unsigned short)v[q]);
    }
  }
  #pragma unroll
  for (int q = 0; q < 8; q++) {
    s[q] += __shfl_xor(s[q], 32);
    s[q] += __shfl_xor(s[q], 16);
    s[q] += __shfl_xor(s[q], 8);
  }
  if (o8 == 0) {
    float inv = 1.f / fmaxf((float)cnt[node], 1.f);
    short8 o;
    #pragma unroll
    for (int q = 0; q < 8; q++) o[q] = (short)f2bf_rtn(s[q] * inv);
    *(short8*)(Oh + (size_t)node * 64 + cg) = o;
  }
}

__global__ __launch_bounds__(256) void k_pull256b(const unsigned short* __restrict__ Xh,
                                                  const int* __restrict__ cnt,
                                                  const int* __restrict__ offs,
                                                  const int* __restrict__ csr,
                                                  unsigned short* __restrict__ Oh) {
  int wid = threadIdx.x >> 6, lane = threadIdx.x & 63;
  int node = blockIdx.x * 4 + wid;
  if (node >= Nn) return;
  int half = lane >> 5;
  int cg = (lane & 31) * 8;
  float s[8] = {0.f, 0.f, 0.f, 0.f, 0.f, 0.f, 0.f, 0.f};
  int j0 = offs[node], j1 = offs[node + 1];
  for (int j = j0; j < j1; j += 2) {
    int e = j + half;
    if (e < j1) {
      short8 v = *(const short8*)(Xh + (size_t)csr[e] * 256 + cg);
      #pragma unroll
      for (int q = 0; q < 8; q++) s[q] += bf2f((unsigned short)v[q]);
    }
  }
  #pragma unroll
  for (int q = 0; q < 8; q++) s[q] += __shfl_xor(s[q], 32);
  if (half == 0) {
    float inv = 1.f / fmaxf((float)cnt[node], 1.f);
    short8 o;
    #pragma unroll
    for (int q = 0; q < 8; q++) o[q] = (short)f2bf_rtn(s[q] * inv);
    *(short8*)(Oh + (size_t)node * 256 + cg) = o;
  }
}

// ---------------- weight prep ----------------
__global__ void k_prep(const float* __restrict__ W, int K, int N,
                       unsigned short* __restrict__ Hi, unsigned short* __restrict__ Lo) {
  int idx = blockIdx.x * 256 + threadIdx.x;
  if (idx >= K * N) return;
  int k = idx / N, n = idx - k * N;
  float x = W[idx];
  unsigned short h = f2bf_rtn(x);
  Hi[(size_t)n * K + k] = h;
  Lo[(size_t)n * K + k] = f2bf_rtn(x - bf2f(h));
}

__global__ void k_bias_pad(const float* __restrict__ b, float* __restrict__ out) {
  int i = threadIdx.x;
  out[i] = (i < 128) ? b[i] : 0.f;
}

// ---------------- bf16-A x split-bf16-B MFMA GEMM, BM=128 BN=256 BK=32, dbuf + LDS-staged epilogue ----------------
template <int PASSES, bool RELU, bool SPLITOUT>
__global__ __launch_bounds__(256, 2) void k_gemm(
    const unsigned short* __restrict__ A1,
    const unsigned short* __restrict__ B1h, const unsigned short* __restrict__ B1l,
    const unsigned short* __restrict__ A2,
    const unsigned short* __restrict__ B2h, const unsigned short* __restrict__ B2l,
    const float* __restrict__ bias,
    unsigned short* __restrict__ Cb, float* __restrict__ S3, unsigned short* __restrict__ P3,
    int K) {
  __shared__ __align__(16) unsigned short smem[40960];   // 80KB: A 2x8KB | Bh 2x16KB | Bl 2x16KB
  const int tid = threadIdx.x;
  const int lane = tid & 63;
  const int wid = tid >> 6;
  const int l15 = lane & 15, l4 = lane >> 4;
  const int wm = (wid >> 1) * 64;
  const int wn2 = (wid & 1) * 128;
  const int row0 = blockIdx.x * 128;
  const int srow = lane >> 2;
  const int sg = ((lane & 3) ^ ((lane >> 3) & 3)) * 8;
  const int gsw = (l4 ^ ((l15 >> 1) & 3)) * 8;

  const int ktiles = K >> 5;
  const int nt = PASSES * ktiles;

  auto Ash = [&](int b) { return smem + b * 4096; };
  auto Bsh = [&](int b) { return smem + 8192 + b * 8192; };
  auto Bsl = [&](int b) { return smem + 24576 + b * 8192; };

  auto stage = [&](int t, int b) {
    int pass = (PASSES == 2 && t >= ktiles) ? 1 : 0;
    int k0 = (t - pass * ktiles) << 5;
    const unsigned short* gA = pass ? A2 : A1;
    const unsigned short* gBh = pass ? B2h : B1h;
    const unsigned short* gBl = pass ? B2l : B1l;
    #pragma unroll
    for (int cc = 0; cc < 10; ++cc) {
      int c = wid * 10 + cc;
      unsigned short* lb;
      const unsigned short* gb;
      int grow;
      if (c < 8)       { lb = Ash(b) + c * 512;               gb = gA;  grow = row0 + c * 16 + srow; }
      else if (c < 24) { int q = c - 8;  lb = Bsh(b) + q * 512; gb = gBh; grow = q * 16 + srow; }
      else             { int q = c - 24; lb = Bsl(b) + q * 512; gb = gBl; grow = q * 16 + srow; }
      __builtin_amdgcn_global_load_lds(
          (const __attribute__((address_space(1))) void*)(gb + (size_t)grow * K + k0 + sg),
          (__attribute__((address_space(3))) void*)lb, 16, 0, 0);
    }
  };

  f32x4 acc[4][8];
  #pragma unroll
  for (int s = 0; s < 4; ++s)
    #pragma unroll
    for (int t = 0; t < 8; ++t) acc[s][t] = (f32x4)0.0f;

  stage(0, 0);
  __syncthreads();
  for (int t = 0; t < nt; ++t) {
    int buf = t & 1;
    if (t + 1 < nt) stage(t + 1, buf ^ 1);
    short8 af[4];
    #pragma unroll
    for (int s = 0; s < 4; ++s)
      af[s] = *(const short8*)&Ash(buf)[(wm + s * 16 + l15) * 32 + gsw];
    #pragma unroll
    for (int tt = 0; tt < 8; ++tt) {
      short8 b = *(const short8*)&Bsh(buf)[(wn2 + tt * 16 + l15) * 32 + gsw];
      #pragma unroll
      for (int s = 0; s < 4; ++s)
        acc[s][tt] = __builtin_amdgcn_mfma_f32_16x16x32_bf16(af[s], b, acc[s][tt], 0, 0, 0);
    }
    #pragma unroll
    for (int tt = 0; tt < 8; ++tt) {
      short8 b = *(const short8*)&Bsl(buf)[(wn2 + tt * 16 + l15) * 32 + gsw];
      #pragma unroll
      for (int s = 0; s < 4; ++s)
        acc[s][tt] = __builtin_amdgcn_mfma_f32_16x16x32_bf16(af[s], b, acc[s][tt], 0, 0, 0);
    }
    __syncthreads();
  }

  // ---- epilogue: stage bf16 output in LDS, then coalesced short8 streams ----
  if (!SPLITOUT) {
    unsigned short* Cs = smem;   // 128x256 bf16 = 64KB
    #pragma unroll
    for (int tt = 0; tt < 8; ++tt) {
      int col = wn2 + tt * 16 + l15;
      float bv = bias[col];
      #pragma unroll
      for (int s = 0; s < 4; ++s) {
        int r = wm + s * 16 + l4 * 4;
        #pragma unroll
        for (int j = 0; j < 4; ++j) {
          float v = acc[s][tt][j] + bv;
          if (RELU) v = fmaxf(v, 0.f);
          Cs[(r + j) * 256 + col] = f2bf_rtn(v);
        }
      }
    }
    __syncthreads();
    #pragma unroll
    for (int it = 0; it < 16; ++it) {
      int ch = it * 256 + tid;          // 4096 chunks of 8 shorts
      int row = row0 + (ch >> 5);
      if (row < Nn)
        *(short8*)(Cb + (size_t)row * 256 + (ch & 31) * 8) = *(const short8*)&Cs[ch * 8];
    }
  } else {
    // cols <128 -> S3 fp32 (direct, 64B-contiguous per quarter-wave); cols >=128 -> P3 bf16 via LDS
    unsigned short* Ps = smem;   // 128x128 bf16 = 32KB
    #pragma unroll
    for (int tt = 0; tt < 8; ++tt) {
      int col = wn2 + tt * 16 + l15;
      float bv = bias[col];
      #pragma unroll
      for (int s = 0; s < 4; ++s) {
        int r = wm + s * 16 + l4 * 4;
        #pragma unroll
        for (int j = 0; j < 4; ++j) {
          float v = acc[s][tt][j] + bv;
          if (RELU) v = fmaxf(v, 0.f);
          int row = row0 + r + j;
          if (wn2 == 0) {
            if (row < Nn) S3[(size_t)row * 128 + col] = v;
          } else {
            Ps[(r + j) * 128 + (col - 128)] = f2bf_rtn(v);
          }
        }
      }
    }
    __syncthreads();
    #pragma unroll
    for (int it = 0; it < 8; ++it) {
      int ch = it * 256 + tid;          // 2048 chunks of 8 shorts
      int row = row0 + (ch >> 4);
      if (row < Nn)
        *(short8*)(P3 + (size_t)row * 128 + (ch & 15) * 8) = *(const short8*)&Ps[ch * 8];
    }
  }
}

// ---------------- fused final: gather P3 + relu(S3 + mean) + classifier ----------------
__global__ __launch_bounds__(256) void k_cls3(const float* __restrict__ S3,
                                              const unsigned short* __restrict__ P3,
                                              const int* __restrict__ cnt,
                                              const int* __restrict__ offs,
                                              const int* __restrict__ csr,
                                              const float* __restrict__ W,
                                              const float* __restrict__ B,
                                              float* __restrict__ out) {
  __shared__ float sw[1024];
  __shared__ float sb[8];
  for (int i = threadIdx.x; i < 1024; i += 256) sw[i] = W[i];
  if (threadIdx.x < 8) sb[threadIdx.x] = B[threadIdx.x];
  __syncthreads();
  int wid = threadIdx.x >> 6, lane = threadIdx.x & 63;
  int node = blockIdx.x * 4 + wid;
  if (node >= Nn) return;
  int q4 = lane >> 4;
  int cg = (lane & 15) * 8;
  float s[8] = {0.f, 0.f, 0.f, 0.f, 0.f, 0.f, 0.f, 0.f};
  int j0 = offs[node], j1 = offs[node + 1];
  for (int j = j0; j < j1; j += 4) {
    int e = j + q4;
    if (e < j1) {
      short8 v = *(const short8*)(P3 + (size_t)csr[e] * 128 + cg);
      #pragma unroll
      for (int q = 0; q < 8; q++) s[q] += bf2f((unsigned short)v[q]);
    }
  }
  #pragma unroll
  for (int q = 0; q < 8; q++) {
    s[q] += __shfl_xor(s[q], 32);
    s[q] += __shfl_xor(s[q], 16);
  }
  float inv = 1.f / fmaxf((float)cnt[node], 1.f);
  const float4* s3p = (const float4*)(S3 + (size_t)node * 128 + cg);
  float4 a0 = s3p[0], a1 = s3p[1];
  float h[8];
  h[0] = fmaxf(a0.x + s[0] * inv, 0.f); h[1] = fmaxf(a0.y + s[1] * inv, 0.f);
  h[2] = fmaxf(a0.z + s[2] * inv, 0.f); h[3] = fmaxf(a0.w + s[3] * inv, 0.f);
  h[4] = fmaxf(a1.x + s[4] * inv, 0.f); h[5] = fmaxf(a1.y + s[5] * inv, 0.f);
  h[6] = fmaxf(a1.z + s[6] * inv, 0.f); h[7] = fmaxf(a1.w + s[7] * inv, 0.f);
  float p[8] = {0.f, 0.f, 0.f, 0.f, 0.f, 0.f, 0.f, 0.f};
  #pragma unroll
  for (int jj = 0; jj < 8; jj++) {
    #pragma unroll
    for (int o = 0; o < 8; o++) p[o] += h[jj] * sw[(cg + jj) * 8 + o];
  }
  #pragma unroll
  for (int o = 0; o < 8; o++) {
    p[o] += __shfl_xor(p[o], 1);
    p[o] += __shfl_xor(p[o], 2);
    p[o] += __shfl_xor(p[o], 4);
    p[o] += __shfl_xor(p[o], 8);
  }
  if (lane == 0) {
    float4* orow = (float4*)(out + (size_t)node * 8);
    orow[0] = make_float4(p[0] + sb[0], p[1] + sb[1], p[2] + sb[2], p[3] + sb[3]);
    orow[1] = make_float4(p[4] + sb[4], p[5] + sb[5], p[6] + sb[6], p[7] + sb[7]);
  }
}

extern "C" void kernel_launch(void* const* d_in, const int* in_sizes, int n_in,
                              void* d_out, int out_size, void* d_ws, size_t ws_size,
                              hipStream_t stream) {
  (void)in_sizes; (void)n_in; (void)out_size; (void)ws_size;
  const float* feat = (const float*)d_in[0];
  const int* eidx = (const int*)d_in[1];
  const int* esrc = eidx;
  const int* edst = eidx + Ee;
  const float* gw1 = (const float*)d_in[2];  const float* gb1 = (const float*)d_in[3];
  const float* gw2 = (const float*)d_in[4];  const float* gb2 = (const float*)d_in[5];
  const float* aw1 = (const float*)d_in[6];  const float* ab1 = (const float*)d_in[7];
  const float* aw2 = (const float*)d_in[8];  const float* ab2 = (const float*)d_in[9];
  const float* c1ws = (const float*)d_in[10]; const float* c1wn = (const float*)d_in[11]; const float* c1b = (const float*)d_in[12];
  const float* c2ws = (const float*)d_in[13]; const float* c2wn = (const float*)d_in[14]; const float* c2b = (const float*)d_in[15];
  const float* c3ws = (const float*)d_in[16]; const float* c3wn = (const float*)d_in[17]; const float* c3b = (const float*)d_in[18];
  const float* clw = (const float*)d_in[19];  const float* clb = (const float*)d_in[20];
  float* out = (float*)d_out;

  char* ws = (char*)d_ws;
  size_t off = 0;
  auto alloc = [&](size_t b) -> char* {
    char* p = ws + off;
    off = (off + b + 255) & ~(size_t)255;
    return p;
  };
  int* cnt = (int*)alloc(Nn * 4);
  int* cur = (int*)alloc(Nn * 4);
  double* accF = (double*)alloc(128 * 8);
  double* accR = (double*)alloc(128 * 8);
  double* accZ = (double*)alloc(128 * 8);
  size_t zbytes = off;  // region above must be zeroed
  int* offs = (int*)alloc((size_t)(Nn + 1) * 4);
  int* csr = (int*)alloc((size_t)Ee * 4);
  int* bsum = (int*)alloc(NBLK * 4);
  int* bbase = (int*)alloc(NBLK * 4);
  float* dinv = (float*)alloc(Nn * 4);
  unsigned short* B1sh = (unsigned short*)alloc(256 * 64 * 2);
  unsigned short* B1sl = (unsigned short*)alloc(256 * 64 * 2);
  unsigned short* B1nh = (unsigned short*)alloc(256 * 64 * 2);
  unsigned short* B1nl = (unsigned short*)alloc(256 * 64 * 2);
  unsigned short* B2sh = (unsigned short*)alloc(256 * 256 * 2);
  unsigned short* B2sl = (unsigned short*)alloc(256 * 256 * 2);
  unsigned short* B2nh = (unsigned short*)alloc(256 * 256 * 2);
  unsigned short* B2nl = (unsigned short*)alloc(256 * 256 * 2);
  unsigned short* B3h = (unsigned short*)alloc(256 * 256 * 2);
  unsigned short* B3l = (unsigned short*)alloc(256 * 256 * 2);
  float* b3p = (float*)alloc(256 * 4);
  float* Xs = (float*)alloc((size_t)Nn * 64 * 4);
  float* Zf = (float*)alloc((size_t)Nn * 64 * 4);
  unsigned short* H0h = (unsigned short*)alloc((size_t)Nn * 64 * 2);
  unsigned short* AG0 = (unsigned short*)alloc((size_t)Nn * 64 * 2);
  unsigned short* H1h = (unsigned short*)alloc((size_t)Nn * 256 * 2);
  unsigned short* AG1 = (unsigned short*)alloc((size_t)Nn * 256 * 2);
  unsigned short* H2h = (unsigned short*)alloc((size_t)Nn * 256 * 2);
  alloc(65536);  // guard for OOB A-row staging (rows 50000..50047)
  float* S3f = (float*)Zf;            // alias (Zf dead after k_attn)
  unsigned short* P3h = AG1;          // alias (AG1 dead after GEMM2)

  hipMemsetAsync(d_ws, 0, zbytes, stream);

  hipLaunchKernelGGL(k_prep, dim3(64), dim3(256), 0, stream, c1ws, 64, 256, B1sh, B1sl);
  hipLaunchKernelGGL(k_prep, dim3(64), dim3(256), 0, stream, c1wn, 64, 256, B1nh, B1nl);
  hipLaunchKernelGGL(k_prep, dim3(256), dim3(256), 0, stream, c2ws, 256, 256, B2sh, B2sl);
  hipLaunchKernelGGL(k_prep, dim3(256), dim3(256), 0, stream, c2wn, 256, 256, B2nh, B2nl);
  hipLaunchKernelGGL(k_prep, dim3(128), dim3(256), 0, stream, c3ws, 256, 128, B3h, B3l);
  hipLaunchKernelGGL(k_prep, dim3(128), dim3(256), 0, stream, c3wn, 256, 128,
                     B3h + 128 * 256, B3l + 128 * 256);
  hipLaunchKernelGGL(k_bias_pad, dim3(1), dim3(256), 0, stream, c3b, b3p);

  int eb = (Ee + 255) / 256;
  hipLaunchKernelGGL(k_count, dim3(eb), dim3(256), 0, stream, edst, cnt);
  hipLaunchKernelGGL(k_bsum, dim3(NBLK), dim3(256), 0, stream, cnt, bsum);
  hipLaunchKernelGGL(k_bscan, dim3(1), dim3(256), 0, stream, bsum, bbase, offs);
  hipLaunchKernelGGL(k_offsets, dim3(NBLK), dim3(256), 0, stream, cnt, bbase, offs, dinv);
  hipLaunchKernelGGL(k_scatter, dim3(eb), dim3(256), 0, stream, esrc, edst, offs, cur, csr);

  hipLaunchKernelGGL((k_stats<true>), dim3(196), dim3(256), 0, stream, feat, accF, dinv, Xs);

  hipLaunchKernelGGL(k_energy, dim3((Nn + 3) / 4), dim3(256), 0, stream,
                     Xs, cnt, offs, csr, Zf);
  hipLaunchKernelGGL((k_stats<false>), dim3(196), dim3(256), 0, stream, Zf, accR,
                     (const float*)nullptr, (float*)nullptr);

  hipLaunchKernelGGL(k_gate, dim3((Nn + 255) / 256), dim3(256), 0, stream,
                     feat, accF, accR, gw1, gb1, gw2, gb2, Zf);
  hipLaunchKernelGGL((k_stats<false>), dim3(196), dim3(256), 0, stream, Zf, accZ,
                     (const float*)nullptr, (float*)nullptr);

  hipLaunchKernelGGL(k_attn, dim3(196), dim3(256), 0, stream,
                     accZ, aw1, ab1, aw2, ab2, Zf, H0h);

  hipLaunchKernelGGL(k_pull64b, dim3((Nn + 3) / 4), dim3(256), 0, stream,
                     H0h, cnt, offs, csr, AG0);
  hipLaunchKernelGGL((k_gemm<2, true, false>), dim3(391), dim3(256), 0, stream,
                     H0h, B1sh, B1sl, AG0, B1nh, B1nl, c1b,
                     H1h, (float*)nullptr, (unsigned short*)nullptr, 64);
  hipLaunchKernelGGL(k_pull256b, dim3((Nn + 3) / 4), dim3(256), 0, stream,
                     H1h, cnt, offs, csr, AG1);
  hipLaunchKernelGGL((k_gemm<2, true, false>), dim3(391), dim3(256), 0, stream,
                     H1h, B2sh, B2sl, AG1, B2nh, B2nl, c2b,
                     H2h, (float*)nullptr, (unsigned short*)nullptr, 256);
  hipLaunchKernelGGL((k_gemm<1, false, true>), dim3(391), dim3(256), 0, stream,
                     H2h, B3h, B3l,
                     (unsigned short*)nullptr, (unsigned short*)nullptr, (unsigned short*)nullptr,
                     b3p, (unsigned short*)nullptr, S3f, P3h, 256);
  hipLaunchKernelGGL(k_cls3, dim3((Nn + 3) / 4), dim3(256), 0, stream,
                     S3f, P3h, cnt, offs, csr, clw, clb, out);
}

// Round 10
// 661.936 us; speedup vs baseline: 1.0133x; 1.0133x over previous
//
#include <hip/hip_runtime.h>
#include <math.h>

constexpr int Nn = 50000;
constexpr int Ee = 800000;
constexpr int NBLK = (Nn + 255) / 256;  // 196

typedef __attribute__((ext_vector_type(8))) short short8;
typedef __attribute__((ext_vector_type(4))) float f32x4;

__device__ inline unsigned short f2bf_rtn(float f) {
  union { float f; unsigned u; } v; v.f = f;
  unsigned r = v.u + 0x7FFFu + ((v.u >> 16) & 1u);
  return (unsigned short)(r >> 16);
}
__device__ inline float bf2f(unsigned short h) {
  union { unsigned u; float f; } v; v.u = ((unsigned)h) << 16;
  return v.f;
}

// ---------------- CSR build ----------------
__global__ void k_count(const int* __restrict__ dst, int* __restrict__ cnt) {
  int e = blockIdx.x * 256 + threadIdx.x;
  if (e < Ee) atomicAdd(&cnt[dst[e]], 1);
}

__global__ __launch_bounds__(256) void k_bsum(const int* __restrict__ cnt, int* __restrict__ bsum) {
  __shared__ int sh[256];
  int i = blockIdx.x * 256 + threadIdx.x;
  int v = (i < Nn) ? cnt[i] : 0;
  sh[threadIdx.x] = v;
  __syncthreads();
  #pragma unroll
  for (int off = 128; off > 0; off >>= 1) {
    if (threadIdx.x < off) sh[threadIdx.x] += sh[threadIdx.x + off];
    __syncthreads();
  }
  if (threadIdx.x == 0) bsum[blockIdx.x] = sh[0];
}

__global__ __launch_bounds__(256) void k_bscan(const int* __restrict__ bsum,
                                               int* __restrict__ bbase, int* __restrict__ offs) {
  __shared__ int sh[256];
  int t = threadIdx.x;
  int v = (t < NBLK) ? bsum[t] : 0;
  sh[t] = v;
  __syncthreads();
  #pragma unroll
  for (int off = 1; off < 256; off <<= 1) {
    int u = (t >= off) ? sh[t - off] : 0;
    __syncthreads();
    sh[t] += u;
    __syncthreads();
  }
  if (t < NBLK) bbase[t] = sh[t] - v;
  if (t == 0) offs[Nn] = Ee;
}

__global__ __launch_bounds__(256) void k_offsets(const int* __restrict__ cnt,
                                                 const int* __restrict__ bbase,
                                                 int* __restrict__ offs, float* __restrict__ dinv) {
  __shared__ int sh[256];
  int i = blockIdx.x * 256 + threadIdx.x;
  int t = threadIdx.x;
  int v = (i < Nn) ? cnt[i] : 0;
  sh[t] = v;
  __syncthreads();
  #pragma unroll
  for (int off = 1; off < 256; off <<= 1) {
    int u = (t >= off) ? sh[t - off] : 0;
    __syncthreads();
    sh[t] += u;
    __syncthreads();
  }
  if (i < Nn) {
    offs[i] = bbase[blockIdx.x] + sh[t] - v;
    dinv[i] = rsqrtf(fmaxf((float)v, 1e-12f));
  }
}

__global__ void k_scatter(const int* __restrict__ src, const int* __restrict__ dst,
                          const int* __restrict__ offs, int* __restrict__ cur,
                          int* __restrict__ csr) {
  int e = blockIdx.x * 256 + threadIdx.x;
  if (e < Ee) {
    int d = dst[e];
    int p = offs[d] + atomicAdd(&cur[d], 1);
    csr[p] = src[e];
  }
}

// ---------------- column stats (64-wide, ddof=1); statsx also emits Xs = feat*dinv ----------------
template <bool EMITXS>
__global__ __launch_bounds__(256) void k_stats(const float* __restrict__ X, double* __restrict__ acc,
                                               const float* __restrict__ dinv, float* __restrict__ Xs) {
  int col = threadIdx.x & 63, rs_ = threadIdx.x >> 6;
  int row0 = blockIdx.x * 256;
  int rend = min(row0 + 256, Nn);
  double s = 0.0, ss = 0.0;
  for (int r = row0 + rs_; r < rend; r += 4) {
    float v = X[(size_t)r * 64 + col];
    if (EMITXS) Xs[(size_t)r * 64 + col] = v * dinv[r];
    s += v; ss += (double)v * v;
  }
  __shared__ double sh[512];
  sh[threadIdx.x] = s; sh[256 + threadIdx.x] = ss;
  __syncthreads();
  if (rs_ == 0) {
    s = sh[col] + sh[col + 64] + sh[col + 128] + sh[col + 192];
    ss = sh[256 + col] + sh[256 + col + 64] + sh[256 + col + 128] + sh[256 + col + 192];
    atomicAdd(&acc[col], s);
    atomicAdd(&acc[64 + col], ss);
  }
}

__device__ inline void stats_final_sh(const double* acc, float* smean, float* srstd, int t) {
  if (t < 64) {
    double s = acc[t], ss = acc[64 + t];
    double m = s / (double)Nn;
    double var = (ss - s * s / (double)Nn) / (double)(Nn - 1);
    double sd = sqrt(var > 0.0 ? var : 0.0);
    if (sd < 1e-8) sd = 1e-8;
    smean[t] = (float)m;
    srstd[t] = (float)(1.0 / sd);
  }
}

// ---------------- local Dirichlet energy ----------------
__global__ __launch_bounds__(256) void k_energy(const float* __restrict__ Xs,
                                                const int* __restrict__ cnt,
                                                const int* __restrict__ offs,
                                                const int* __restrict__ csr,
                                                float* __restrict__ R) {
  int wid = threadIdx.x >> 6, lane = threadIdx.x & 63;
  int node = blockIdx.x * 4 + wid;
  if (node >= Nn) return;
  int q4 = lane >> 4;
  int cg = (lane & 15) * 4;
  float4 xi = *(const float4*)(Xs + (size_t)node * 64 + cg);
  float num[4] = {0.f, 0.f, 0.f, 0.f}, den[4] = {0.f, 0.f, 0.f, 0.f};
  int j0 = offs[node], j1 = offs[node + 1];
  for (int j = j0; j < j1; j += 4) {
    int e = j + q4;
    if (e < j1) {
      float4 xs = *(const float4*)(Xs + (size_t)csr[e] * 64 + cg);
      float d0 = xi.x - xs.x, d1 = xi.y - xs.y, d2 = xi.z - xs.z, d3 = xi.w - xs.w;
      num[0] += d0 * d0; num[1] += d1 * d1; num[2] += d2 * d2; num[3] += d3 * d3;
      den[0] += xs.x * xs.x; den[1] += xs.y * xs.y; den[2] += xs.z * xs.z; den[3] += xs.w * xs.w;
    }
  }
  #pragma unroll
  for (int c = 0; c < 4; c++) {
    num[c] += __shfl_xor(num[c], 32); num[c] += __shfl_xor(num[c], 16);
    den[c] += __shfl_xor(den[c], 32); den[c] += __shfl_xor(den[c], 16);
  }
  if (q4 == 0) {
    float degf = (float)cnt[node];
    float4 o;
    o.x = num[0] / (den[0] + degf * xi.x * xi.x + 1e-8f);
    o.y = num[1] / (den[1] + degf * xi.y * xi.y + 1e-8f);
    o.z = num[2] / (den[2] + degf * xi.z * xi.z + 1e-8f);
    o.w = num[3] / (den[3] + degf * xi.w * xi.w + 1e-8f);
    *(float4*)(R + (size_t)node * 64 + cg) = o;
  }
}

// ---------------- gate MLP + Z (in-place R -> Z, fp32) ----------------
__global__ __launch_bounds__(256) void k_gate(const float* __restrict__ feat,
                                              const double* __restrict__ accF,
                                              const double* __restrict__ accR,
                                              const float* __restrict__ w1, const float* __restrict__ b1,
                                              const float* __restrict__ w2, const float* __restrict__ b2,
                                              float* __restrict__ RZ) {
  __shared__ float sw1[1024], sw2[1024], sb1[16], sb2[64], sfm[64], sfr[64], srm[64], srr[64];
  for (int i = threadIdx.x; i < 1024; i += 256) { sw1[i] = w1[i]; sw2[i] = w2[i]; }
  if (threadIdx.x < 16) sb1[threadIdx.x] = b1[threadIdx.x];
  if (threadIdx.x < 64) sb2[threadIdx.x] = b2[threadIdx.x];
  stats_final_sh(accF, sfm, sfr, threadIdx.x);
  stats_final_sh(accR, srm, srr, threadIdx.x);
  __syncthreads();
  int node = blockIdx.x * 256 + threadIdx.x;
  if (node >= Nn) return;
  float xn[64];
  const float4* fx = (const float4*)(feat + (size_t)node * 64);
  for (int q = 0; q < 16; q++) {
    float4 v = fx[q];
    xn[q * 4 + 0] = (v.x - sfm[q * 4 + 0]) * sfr[q * 4 + 0];
    xn[q * 4 + 1] = (v.y - sfm[q * 4 + 1]) * sfr[q * 4 + 1];
    xn[q * 4 + 2] = (v.z - sfm[q * 4 + 2]) * sfr[q * 4 + 2];
    xn[q * 4 + 3] = (v.w - sfm[q * 4 + 3]) * sfr[q * 4 + 3];
  }
  float hid[16];
  #pragma unroll
  for (int h = 0; h < 16; h++) {
    float a = sb1[h];
    #pragma unroll
    for (int k = 0; k < 64; k++) a += xn[k] * sw1[k * 16 + h];
    hid[h] = fmaxf(a, 0.f);
  }
  float4* row = (float4*)(RZ + (size_t)node * 64);
  for (int q = 0; q < 16; q++) {
    float4 rv = row[q];
    float Rv[4] = {rv.x, rv.y, rv.z, rv.w};
    float zo[4];
    #pragma unroll
    for (int j = 0; j < 4; j++) {
      int o = q * 4 + j;
      float a = sb2[o];
      #pragma unroll
      for (int h = 0; h < 16; h++) a += hid[h] * sw2[h * 64 + o];
      float g = 1.f / (1.f + expf(-a));
      float Rn = (Rv[j] - srm[o]) * srr[o];
      float Rf = (2.f - Rv[j] - srm[o]) * srr[o];
      zo[j] = g * Rn + (1.f - g) * Rf;
    }
    row[q] = make_float4(zo[0], zo[1], zo[2], zo[3]);
  }
}

// ---------------- attn MLP + h0 = en*attn (Z fp32 -> H0 bf16, coalesced store) ----------------
__global__ __launch_bounds__(256) void k_attn(const double* __restrict__ accZ,
                                              const float* __restrict__ w1, const float* __restrict__ b1,
                                              const float* __restrict__ w2, const float* __restrict__ b2,
                                              const float* __restrict__ Zf,
                                              unsigned short* __restrict__ Hh) {
  __shared__ float sw1[1024], sw2[1024], sb1[16], sb2[64], szm[64], szr[64];
  __shared__ unsigned short sout[256][72];
  for (int i = threadIdx.x; i < 1024; i += 256) { sw1[i] = w1[i]; sw2[i] = w2[i]; }
  if (threadIdx.x < 16) sb1[threadIdx.x] = b1[threadIdx.x];
  if (threadIdx.x < 64) sb2[threadIdx.x] = b2[threadIdx.x];
  stats_final_sh(accZ, szm, szr, threadIdx.x);
  __syncthreads();
  int node0 = blockIdx.x * 256;
  int node = node0 + threadIdx.x;
  if (node < Nn) {
    float en[64];
    const float4* row = (const float4*)(Zf + (size_t)node * 64);
    for (int q = 0; q < 16; q++) {
      float4 v = row[q];
      en[q * 4 + 0] = (v.x - szm[q * 4 + 0]) * szr[q * 4 + 0];
      en[q * 4 + 1] = (v.y - szm[q * 4 + 1]) * szr[q * 4 + 1];
      en[q * 4 + 2] = (v.z - szm[q * 4 + 2]) * szr[q * 4 + 2];
      en[q * 4 + 3] = (v.w - szm[q * 4 + 3]) * szr[q * 4 + 3];
    }
    float hid[16];
    #pragma unroll
    for (int h = 0; h < 16; h++) {
      float a = sb1[h];
      #pragma unroll
      for (int k = 0; k < 64; k++) a += en[k] * sw1[k * 16 + h];
      hid[h] = fmaxf(a, 0.f);
    }
    for (int q = 0; q < 16; q++) {
      #pragma unroll
      for (int j = 0; j < 4; j++) {
        int o = q * 4 + j;
        float a = sb2[o];
        #pragma unroll
        for (int h = 0; h < 16; h++) a += hid[h] * sw2[h * 64 + o];
        float att = 1.f / (1.f + expf(-a));
        sout[threadIdx.x][o] = f2bf_rtn(en[o] * att);
      }
    }
  }
  __syncthreads();
  int nval = (min(Nn - node0, 256)) * 64;
  for (int base = 0; base < 16384; base += 2048) {
    int i = base + threadIdx.x * 8;
    if (i < nval) {
      int r = i >> 6, c = i & 63;
      *(short8*)(Hh + (size_t)node0 * 64 + i) = *(const short8*)&sout[r][c];
    }
  }
}

// ---------------- neighbor-mean pulls ----------------
__global__ __launch_bounds__(256) void k_pull64b(const unsigned short* __restrict__ Xh,
                                                 const int* __restrict__ cnt,
                                                 const int* __restrict__ offs,
                                                 const int* __restrict__ csr,
                                                 unsigned short* __restrict__ Oh) {
  int wid = threadIdx.x >> 6, lane = threadIdx.x & 63;
  int node = blockIdx.x * 4 + wid;
  if (node >= Nn) return;
  int o8 = lane >> 3;
  int cg = (lane & 7) * 8;
  float s[8] = {0.f, 0.f, 0.f, 0.f, 0.f, 0.f, 0.f, 0.f};
  int j0 = offs[node], j1 = offs[node + 1];
  for (int j = j0; j < j1; j += 8) {
    int e = j + o8;
    if (e < j1) {
      short8 v = *(const short8*)(Xh + (size_t)csr[e] * 64 + cg);
      #pragma unroll
      for (int q = 0; q < 8; q++) s[q] += bf2f((unsigned short)v[q]);
    }
  }
  #pragma unroll
  for (int q = 0; q < 8; q++) {
    s[q] += __shfl_xor(s[q], 32);
    s[q] += __shfl_xor(s[q], 16);
    s[q] += __shfl_xor(s[q], 8);
  }
  if (o8 == 0) {
    float inv = 1.f / fmaxf((float)cnt[node], 1.f);
    short8 o;
    #pragma unroll
    for (int q = 0; q < 8; q++) o[q] = (short)f2bf_rtn(s[q] * inv);
    *(short8*)(Oh + (size_t)node * 64 + cg) = o;
  }
}

__global__ __launch_bounds__(256) void k_pull256b(const unsigned short* __restrict__ Xh,
                                                  const int* __restrict__ cnt,
                                                  const int* __restrict__ offs,
                                                  const int* __restrict__ csr,
                                                  unsigned short* __restrict__ Oh) {
  int wid = threadIdx.x >> 6, lane = threadIdx.x & 63;
  int node = blockIdx.x * 4 + wid;
  if (node >= Nn) return;
  int half = lane >> 5;
  int cg = (lane & 31) * 8;
  float s[8] = {0.f, 0.f, 0.f, 0.f, 0.f, 0.f, 0.f, 0.f};
  int j0 = offs[node], j1 = offs[node + 1];
  for (int j = j0; j < j1; j += 2) {
    int e = j + half;
    if (e < j1) {
      short8 v = *(const short8*)(Xh + (size_t)csr[e] * 256 + cg);
      #pragma unroll
      for (int q = 0; q < 8; q++) s[q] += bf2f((unsigned short)v[q]);
    }
  }
  #pragma unroll
  for (int q = 0; q < 8; q++) s[q] += __shfl_xor(s[q], 32);
  if (half == 0) {
    float inv = 1.f / fmaxf((float)cnt[node], 1.f);
    short8 o;
    #pragma unroll
    for (int q = 0; q < 8; q++) o[q] = (short)f2bf_rtn(s[q] * inv);
    *(short8*)(Oh + (size_t)node * 256 + cg) = o;
  }
}

// ---------------- weight prep ----------------
__global__ void k_prep(const float* __restrict__ W, int K, int N,
                       unsigned short* __restrict__ Hi, unsigned short* __restrict__ Lo) {
  int idx = blockIdx.x * 256 + threadIdx.x;
  if (idx >= K * N) return;
  int k = idx / N, n = idx - k * N;
  float x = W[idx];
  unsigned short h = f2bf_rtn(x);
  Hi[(size_t)n * K + k] = h;
  Lo[(size_t)n * K + k] = f2bf_rtn(x - bf2f(h));
}

__global__ void k_bias_pad(const float* __restrict__ b, float* __restrict__ out) {
  int i = threadIdx.x;
  out[i] = (i < 128) ? b[i] : 0.f;
}

// ---------------- bf16-A x split-bf16-B MFMA GEMM, BM=64 BN=256 BK=32, dbuf + LDS epilogue ----------------
// LDS layout (72KB, ushort offsets): Ash[b] @ b*2048 (2KB each plane is 64x32=2048)
//                                    Bsh[b] @ 4096 + b*8192 (256x32=8192 each)
//                                    Bsl[b] @ 20480 + b*8192
template <int PASSES, bool RELU, bool SPLITOUT>
__global__ __launch_bounds__(256, 2) void k_gemm(
    const unsigned short* __restrict__ A1,
    const unsigned short* __restrict__ B1h, const unsigned short* __restrict__ B1l,
    const unsigned short* __restrict__ A2,
    const unsigned short* __restrict__ B2h, const unsigned short* __restrict__ B2l,
    const float* __restrict__ bias,
    unsigned short* __restrict__ Cb, float* __restrict__ S3, unsigned short* __restrict__ P3,
    int K) {
  __shared__ __align__(16) unsigned short smem[36864];   // 72KB
  const int tid = threadIdx.x;
  const int lane = tid & 63;
  const int wid = tid >> 6;
  const int l15 = lane & 15, l4 = lane >> 4;
  const int wm = (wid >> 1) * 32;        // wave row offset (0/32)
  const int wn2 = (wid & 1) * 128;       // wave col offset (0/128)
  const int row0 = blockIdx.x * 64;
  const int srow = lane >> 2;
  const int sg = ((lane & 3) ^ ((lane >> 3) & 3)) * 8;
  const int gsw = (l4 ^ ((l15 >> 1) & 3)) * 8;

  const int ktiles = K >> 5;
  const int nt = PASSES * ktiles;

  auto Ash = [&](int b) { return smem + b * 2048; };
  auto Bsh = [&](int b) { return smem + 4096 + b * 8192; };
  auto Bsl = [&](int b) { return smem + 20480 + b * 8192; };

  auto stage = [&](int t, int b) {
    int pass = (PASSES == 2 && t >= ktiles) ? 1 : 0;
    int k0 = (t - pass * ktiles) << 5;
    const unsigned short* gA = pass ? A2 : A1;
    const unsigned short* gBh = pass ? B2h : B1h;
    const unsigned short* gBl = pass ? B2l : B1l;
    #pragma unroll
    for (int cc = 0; cc < 9; ++cc) {
      int c = wid * 9 + cc;
      unsigned short* lb;
      const unsigned short* gb;
      int grow;
      if (c < 4)       { lb = Ash(b) + c * 512;               gb = gA;  grow = row0 + c * 16 + srow; }
      else if (c < 20) { int q = c - 4;  lb = Bsh(b) + q * 512; gb = gBh; grow = q * 16 + srow; }
      else             { int q = c - 20; lb = Bsl(b) + q * 512; gb = gBl; grow = q * 16 + srow; }
      __builtin_amdgcn_global_load_lds(
          (const __attribute__((address_space(1))) void*)(gb + (size_t)grow * K + k0 + sg),
          (__attribute__((address_space(3))) void*)lb, 16, 0, 0);
    }
  };

  f32x4 acc[2][8];
  #pragma unroll
  for (int s = 0; s < 2; ++s)
    #pragma unroll
    for (int t = 0; t < 8; ++t) acc[s][t] = (f32x4)0.0f;

  stage(0, 0);
  __syncthreads();
  for (int t = 0; t < nt; ++t) {
    int buf = t & 1;
    if (t + 1 < nt) stage(t + 1, buf ^ 1);
    short8 af[2];
    #pragma unroll
    for (int s = 0; s < 2; ++s)
      af[s] = *(const short8*)&Ash(buf)[(wm + s * 16 + l15) * 32 + gsw];
    #pragma unroll
    for (int tt = 0; tt < 8; ++tt) {
      short8 b = *(const short8*)&Bsh(buf)[(wn2 + tt * 16 + l15) * 32 + gsw];
      #pragma unroll
      for (int s = 0; s < 2; ++s)
        acc[s][tt] = __builtin_amdgcn_mfma_f32_16x16x32_bf16(af[s], b, acc[s][tt], 0, 0, 0);
    }
    #pragma unroll
    for (int tt = 0; tt < 8; ++tt) {
      short8 b = *(const short8*)&Bsl(buf)[(wn2 + tt * 16 + l15) * 32 + gsw];
      #pragma unroll
      for (int s = 0; s < 2; ++s)
        acc[s][tt] = __builtin_amdgcn_mfma_f32_16x16x32_bf16(af[s], b, acc[s][tt], 0, 0, 0);
    }
    __syncthreads();
  }

  // ---- epilogue: stage bf16 output in LDS, then coalesced short8 streams ----
  if (!SPLITOUT) {
    unsigned short* Cs = smem;   // 64x256 bf16 = 32KB
    #pragma unroll
    for (int tt = 0; tt < 8; ++tt) {
      int col = wn2 + tt * 16 + l15;
      float bv = bias[col];
      #pragma unroll
      for (int s = 0; s < 2; ++s) {
        int r = wm + s * 16 + l4 * 4;
        #pragma unroll
        for (int j = 0; j < 4; ++j) {
          float v = acc[s][tt][j] + bv;
          if (RELU) v = fmaxf(v, 0.f);
          Cs[(r + j) * 256 + col] = f2bf_rtn(v);
        }
      }
    }
    __syncthreads();
    #pragma unroll
    for (int it = 0; it < 8; ++it) {
      int ch = it * 256 + tid;          // 2048 chunks of 8 shorts
      int row = row0 + (ch >> 5);
      if (row < Nn)
        *(short8*)(Cb + (size_t)row * 256 + (ch & 31) * 8) = *(const short8*)&Cs[ch * 8];
    }
  } else {
    unsigned short* Ps = smem;   // 64x128 bf16 = 16KB
    #pragma unroll
    for (int tt = 0; tt < 8; ++tt) {
      int col = wn2 + tt * 16 + l15;
      float bv = bias[col];
      #pragma unroll
      for (int s = 0; s < 2; ++s) {
        int r = wm + s * 16 + l4 * 4;
        #pragma unroll
        for (int j = 0; j < 4; ++j) {
          float v = acc[s][tt][j] + bv;
          if (RELU) v = fmaxf(v, 0.f);
          int row = row0 + r + j;
          if (wn2 == 0) {
            if (row < Nn) S3[(size_t)row * 128 + col] = v;
          } else {
            Ps[(r + j) * 128 + (col - 128)] = f2bf_rtn(v);
          }
        }
      }
    }
    __syncthreads();
    #pragma unroll
    for (int it = 0; it < 4; ++it) {
      int ch = it * 256 + tid;          // 1024 chunks of 8 shorts
      int row = row0 + (ch >> 4);
      if (row < Nn)
        *(short8*)(P3 + (size_t)row * 128 + (ch & 15) * 8) = *(const short8*)&Ps[ch * 8];
    }
  }
}

// ---------------- fused final: gather P3 + relu(S3 + mean) + classifier (reg weights) ----------------
__global__ __launch_bounds__(256) void k_cls3(const float* __restrict__ S3,
                                              const unsigned short* __restrict__ P3,
                                              const int* __restrict__ cnt,
                                              const int* __restrict__ offs,
                                              const int* __restrict__ csr,
                                              const float* __restrict__ W,
                                              const float* __restrict__ B,
                                              float* __restrict__ out) {
  int wid = threadIdx.x >> 6, lane = threadIdx.x & 63;
  int node = blockIdx.x * 4 + wid;
  if (node >= Nn) return;
  int q4 = lane >> 4;
  int cg = (lane & 15) * 8;
  float4 wreg[8][2];
  #pragma unroll
  for (int jj = 0; jj < 8; jj++) {
    wreg[jj][0] = *(const float4*)&W[(cg + jj) * 8];
    wreg[jj][1] = *(const float4*)&W[(cg + jj) * 8 + 4];
  }
  float s[8] = {0.f, 0.f, 0.f, 0.f, 0.f, 0.f, 0.f, 0.f};
  int j0 = offs[node], j1 = offs[node + 1];
  for (int j = j0; j < j1; j += 4) {
    int e = j + q4;
    if (e < j1) {
      short8 v = *(const short8*)(P3 + (size_t)csr[e] * 128 + cg);
      #pragma unroll
      for (int q = 0; q < 8; q++) s[q] += bf2f((unsigned short)v[q]);
    }
  }
  #pragma unroll
  for (int q = 0; q < 8; q++) {
    s[q] += __shfl_xor(s[q], 32);
    s[q] += __shfl_xor(s[q], 16);
  }
  float inv = 1.f / fmaxf((float)cnt[node], 1.f);
  const float4* s3p = (const float4*)(S3 + (size_t)node * 128 + cg);
  float4 a0 = s3p[0], a1 = s3p[1];
  float h[8];
  h[0] = fmaxf(a0.x + s[0] * inv, 0.f); h[1] = fmaxf(a0.y + s[1] * inv, 0.f);
  h[2] = fmaxf(a0.z + s[2] * inv, 0.f); h[3] = fmaxf(a0.w + s[3] * inv, 0.f);
  h[4] = fmaxf(a1.x + s[4] * inv, 0.f); h[5] = fmaxf(a1.y + s[5] * inv, 0.f);
  h[6] = fmaxf(a1.z + s[6] * inv, 0.f); h[7] = fmaxf(a1.w + s[7] * inv, 0.f);
  float p[8] = {0.f, 0.f, 0.f, 0.f, 0.f, 0.f, 0.f, 0.f};
  #pragma unroll
  for (int jj = 0; jj < 8; jj++) {
    p[0] += h[jj] * wreg[jj][0].x; p[1] += h[jj] * wreg[jj][0].y;
    p[2] += h[jj] * wreg[jj][0].z; p[3] += h[jj] * wreg[jj][0].w;
    p[4] += h[jj] * wreg[jj][1].x; p[5] += h[jj] * wreg[jj][1].y;
    p[6] += h[jj] * wreg[jj][1].z; p[7] += h[jj] * wreg[jj][1].w;
  }
  #pragma unroll
  for (int o = 0; o < 8; o++) {
    p[o] += __shfl_xor(p[o], 1);
    p[o] += __shfl_xor(p[o], 2);
    p[o] += __shfl_xor(p[o], 4);
    p[o] += __shfl_xor(p[o], 8);
  }
  if (lane == 0) {
    float4* orow = (float4*)(out + (size_t)node * 8);
    orow[0] = make_float4(p[0] + B[0], p[1] + B[1], p[2] + B[2], p[3] + B[3]);
    orow[1] = make_float4(p[4] + B[4], p[5] + B[5], p[6] + B[6], p[7] + B[7]);
  }
}

extern "C" void kernel_launch(void* const* d_in, const int* in_sizes, int n_in,
                              void* d_out, int out_size, void* d_ws, size_t ws_size,
                              hipStream_t stream) {
  (void)in_sizes; (void)n_in; (void)out_size; (void)ws_size;
  const float* feat = (const float*)d_in[0];
  const int* eidx = (const int*)d_in[1];
  const int* esrc = eidx;
  const int* edst = eidx + Ee;
  const float* gw1 = (const float*)d_in[2];  const float* gb1 = (const float*)d_in[3];
  const float* gw2 = (const float*)d_in[4];  const float* gb2 = (const float*)d_in[5];
  const float* aw1 = (const float*)d_in[6];  const float* ab1 = (const float*)d_in[7];
  const float* aw2 = (const float*)d_in[8];  const float* ab2 = (const float*)d_in[9];
  const float* c1ws = (const float*)d_in[10]; const float* c1wn = (const float*)d_in[11]; const float* c1b = (const float*)d_in[12];
  const float* c2ws = (const float*)d_in[13]; const float* c2wn = (const float*)d_in[14]; const float* c2b = (const float*)d_in[15];
  const float* c3ws = (const float*)d_in[16]; const float* c3wn = (const float*)d_in[17]; const float* c3b = (const float*)d_in[18];
  const float* clw = (const float*)d_in[19];  const float* clb = (const float*)d_in[20];
  float* out = (float*)d_out;

  char* ws = (char*)d_ws;
  size_t off = 0;
  auto alloc = [&](size_t b) -> char* {
    char* p = ws + off;
    off = (off + b + 255) & ~(size_t)255;
    return p;
  };
  int* cnt = (int*)alloc(Nn * 4);
  int* cur = (int*)alloc(Nn * 4);
  double* accF = (double*)alloc(128 * 8);
  double* accR = (double*)alloc(128 * 8);
  double* accZ = (double*)alloc(128 * 8);
  size_t zbytes = off;  // region above must be zeroed
  int* offs = (int*)alloc((size_t)(Nn + 1) * 4);
  int* csr = (int*)alloc((size_t)Ee * 4);
  int* bsum = (int*)alloc(NBLK * 4);
  int* bbase = (int*)alloc(NBLK * 4);
  float* dinv = (float*)alloc(Nn * 4);
  unsigned short* B1sh = (unsigned short*)alloc(256 * 64 * 2);
  unsigned short* B1sl = (unsigned short*)alloc(256 * 64 * 2);
  unsigned short* B1nh = (unsigned short*)alloc(256 * 64 * 2);
  unsigned short* B1nl = (unsigned short*)alloc(256 * 64 * 2);
  unsigned short* B2sh = (unsigned short*)alloc(256 * 256 * 2);
  unsigned short* B2sl = (unsigned short*)alloc(256 * 256 * 2);
  unsigned short* B2nh = (unsigned short*)alloc(256 * 256 * 2);
  unsigned short* B2nl = (unsigned short*)alloc(256 * 256 * 2);
  unsigned short* B3h = (unsigned short*)alloc(256 * 256 * 2);
  unsigned short* B3l = (unsigned short*)alloc(256 * 256 * 2);
  float* b3p = (float*)alloc(256 * 4);
  float* Xs = (float*)alloc((size_t)Nn * 64 * 4);
  float* Zf = (float*)alloc((size_t)Nn * 64 * 4);
  unsigned short* H0h = (unsigned short*)alloc((size_t)Nn * 64 * 2);
  unsigned short* AG0 = (unsigned short*)alloc((size_t)Nn * 64 * 2);
  unsigned short* H1h = (unsigned short*)alloc((size_t)Nn * 256 * 2);
  unsigned short* AG1 = (unsigned short*)alloc((size_t)Nn * 256 * 2);
  unsigned short* H2h = (unsigned short*)alloc((size_t)Nn * 256 * 2);
  alloc(65536);  // guard for OOB A-row staging
  float* S3f = (float*)Zf;            // alias (Zf dead after k_attn)
  unsigned short* P3h = AG1;          // alias (AG1 dead after GEMM2)

  hipMemsetAsync(d_ws, 0, zbytes, stream);

  hipLaunchKernelGGL(k_prep, dim3(64), dim3(256), 0, stream, c1ws, 64, 256, B1sh, B1sl);
  hipLaunchKernelGGL(k_prep, dim3(64), dim3(256), 0, stream, c1wn, 64, 256, B1nh, B1nl);
  hipLaunchKernelGGL(k_prep, dim3(256), dim3(256), 0, stream, c2ws, 256, 256, B2sh, B2sl);
  hipLaunchKernelGGL(k_prep, dim3(256), dim3(256), 0, stream, c2wn, 256, 256, B2nh, B2nl);
  hipLaunchKernelGGL(k_prep, dim3(128), dim3(256), 0, stream, c3ws, 256, 128, B3h, B3l);
  hipLaunchKernelGGL(k_prep, dim3(128), dim3(256), 0, stream, c3wn, 256, 128,
                     B3h + 128 * 256, B3l + 128 * 256);
  hipLaunchKernelGGL(k_bias_pad, dim3(1), dim3(256), 0, stream, c3b, b3p);

  int eb = (Ee + 255) / 256;
  hipLaunchKernelGGL(k_count, dim3(eb), dim3(256), 0, stream, edst, cnt);
  hipLaunchKernelGGL(k_bsum, dim3(NBLK), dim3(256), 0, stream, cnt, bsum);
  hipLaunchKernelGGL(k_bscan, dim3(1), dim3(256), 0, stream, bsum, bbase, offs);
  hipLaunchKernelGGL(k_offsets, dim3(NBLK), dim3(256), 0, stream, cnt, bbase, offs, dinv);
  hipLaunchKernelGGL(k_scatter, dim3(eb), dim3(256), 0, stream, esrc, edst, offs, cur, csr);

  hipLaunchKernelGGL((k_stats<true>), dim3(196), dim3(256), 0, stream, feat, accF, dinv, Xs);

  hipLaunchKernelGGL(k_energy, dim3((Nn + 3) / 4), dim3(256), 0, stream,
                     Xs, cnt, offs, csr, Zf);
  hipLaunchKernelGGL((k_stats<false>), dim3(196), dim3(256), 0, stream, Zf, accR,
                     (const float*)nullptr, (float*)nullptr);

  hipLaunchKernelGGL(k_gate, dim3((Nn + 255) / 256), dim3(256), 0, stream,
                     feat, accF, accR, gw1, gb1, gw2, gb2, Zf);
  hipLaunchKernelGGL((k_stats<false>), dim3(196), dim3(256), 0, stream, Zf, accZ,
                     (const float*)nullptr, (float*)nullptr);

  hipLaunchKernelGGL(k_attn, dim3(196), dim3(256), 0, stream,
                     accZ, aw1, ab1, aw2, ab2, Zf, H0h);

  hipLaunchKernelGGL(k_pull64b, dim3((Nn + 3) / 4), dim3(256), 0, stream,
                     H0h, cnt, offs, csr, AG0);
  hipLaunchKernelGGL((k_gemm<2, true, false>), dim3(782), dim3(256), 0, stream,
                     H0h, B1sh, B1sl, AG0, B1nh, B1nl, c1b,
                     H1h, (float*)nullptr, (unsigned short*)nullptr, 64);
  hipLaunchKernelGGL(k_pull256b, dim3((Nn + 3) / 4), dim3(256), 0, stream,
                     H1h, cnt, offs, csr, AG1);
  hipLaunchKernelGGL((k_gemm<2, true, false>), dim3(782), dim3(256), 0, stream,
                     H1h, B2sh, B2sl, AG1, B2nh, B2nl, c2b,
                     H2h, (float*)nullptr, (unsigned short*)nullptr, 256);
  hipLaunchKernelGGL((k_gemm<1, false, true>), dim3(782), dim3(256), 0, stream,
                     H2h, B3h, B3l,
                     (unsigned short*)nullptr, (unsigned short*)nullptr, (unsigned short*)nullptr,
                     b3p, (unsigned short*)nullptr, S3f, P3h, 256);
  hipLaunchKernelGGL(k_cls3, dim3((Nn + 3) / 4), dim3(256), 0, stream,
                     S3f, P3h, cnt, offs, csr, clw, clb, out);
}

// Round 12
// 572.318 us; speedup vs baseline: 1.1720x; 1.1566x over previous
//
#include <hip/hip_runtime.h>
#include <math.h>

constexpr int Nn = 50000;
constexpr int Ee = 800000;
constexpr int NBLK = (Nn + 255) / 256;  // 196

typedef __attribute__((ext_vector_type(8))) short short8;
typedef __attribute__((ext_vector_type(4))) float f32x4;

__device__ inline unsigned short f2bf_rtn(float f) {
  union { float f; unsigned u; } v; v.f = f;
  unsigned r = v.u + 0x7FFFu + ((v.u >> 16) & 1u);
  return (unsigned short)(r >> 16);
}
__device__ inline float bf2f(unsigned short h) {
  union { unsigned u; float f; } v; v.u = ((unsigned)h) << 16;
  return v.f;
}

// ---------------- CSR build ----------------
__global__ void k_count(const int* __restrict__ dst, int* __restrict__ cnt) {
  int e = blockIdx.x * 256 + threadIdx.x;
  if (e < Ee) atomicAdd(&cnt[dst[e]], 1);
}

__global__ __launch_bounds__(256) void k_bsum(const int* __restrict__ cnt, int* __restrict__ bsum) {
  __shared__ int sh[256];
  int i = blockIdx.x * 256 + threadIdx.x;
  int v = (i < Nn) ? cnt[i] : 0;
  sh[threadIdx.x] = v;
  __syncthreads();
  #pragma unroll
  for (int off = 128; off > 0; off >>= 1) {
    if (threadIdx.x < off) sh[threadIdx.x] += sh[threadIdx.x + off];
    __syncthreads();
  }
  if (threadIdx.x == 0) bsum[blockIdx.x] = sh[0];
}

__global__ __launch_bounds__(256) void k_bscan(const int* __restrict__ bsum,
                                               int* __restrict__ bbase, int* __restrict__ offs) {
  __shared__ int sh[256];
  int t = threadIdx.x;
  int v = (t < NBLK) ? bsum[t] : 0;
  sh[t] = v;
  __syncthreads();
  #pragma unroll
  for (int off = 1; off < 256; off <<= 1) {
    int u = (t >= off) ? sh[t - off] : 0;
    __syncthreads();
    sh[t] += u;
    __syncthreads();
  }
  if (t < NBLK) bbase[t] = sh[t] - v;
  if (t == 0) offs[Nn] = Ee;
}

__global__ __launch_bounds__(256) void k_offsets(const int* __restrict__ cnt,
                                                 const int* __restrict__ bbase,
                                                 int* __restrict__ offs, float* __restrict__ dinv) {
  __shared__ int sh[256];
  int i = blockIdx.x * 256 + threadIdx.x;
  int t = threadIdx.x;
  int v = (i < Nn) ? cnt[i] : 0;
  sh[t] = v;
  __syncthreads();
  #pragma unroll
  for (int off = 1; off < 256; off <<= 1) {
    int u = (t >= off) ? sh[t - off] : 0;
    __syncthreads();
    sh[t] += u;
    __syncthreads();
  }
  if (i < Nn) {
    offs[i] = bbase[blockIdx.x] + sh[t] - v;
    dinv[i] = rsqrtf(fmaxf((float)v, 1e-12f));
  }
}

__global__ void k_scatter(const int* __restrict__ src, const int* __restrict__ dst,
                          const int* __restrict__ offs, int* __restrict__ cur,
                          int* __restrict__ csr) {
  int e = blockIdx.x * 256 + threadIdx.x;
  if (e < Ee) {
    int d = dst[e];
    int p = offs[d] + atomicAdd(&cur[d], 1);
    csr[p] = src[e];
  }
}

// ---------------- column stats (64-wide, ddof=1); statsx also emits Xs = feat*dinv ----------------
template <bool EMITXS>
__global__ __launch_bounds__(256) void k_stats(const float* __restrict__ X, double* __restrict__ acc,
                                               const float* __restrict__ dinv, float* __restrict__ Xs) {
  int col = threadIdx.x & 63, rs_ = threadIdx.x >> 6;
  int row0 = blockIdx.x * 256;
  int rend = min(row0 + 256, Nn);
  double s = 0.0, ss = 0.0;
  for (int r = row0 + rs_; r < rend; r += 4) {
    float v = X[(size_t)r * 64 + col];
    if (EMITXS) Xs[(size_t)r * 64 + col] = v * dinv[r];
    s += v; ss += (double)v * v;
  }
  __shared__ double sh[512];
  sh[threadIdx.x] = s; sh[256 + threadIdx.x] = ss;
  __syncthreads();
  if (rs_ == 0) {
    s = sh[col] + sh[col + 64] + sh[col + 128] + sh[col + 192];
    ss = sh[256 + col] + sh[256 + col + 64] + sh[256 + col + 128] + sh[256 + col + 192];
    atomicAdd(&acc[col], s);
    atomicAdd(&acc[64 + col], ss);
  }
}

__device__ inline void stats_final_sh(const double* acc, float* smean, float* srstd, int t) {
  if (t < 64) {
    double s = acc[t], ss = acc[64 + t];
    double m = s / (double)Nn;
    double var = (ss - s * s / (double)Nn) / (double)(Nn - 1);
    double sd = sqrt(var > 0.0 ? var : 0.0);
    if (sd < 1e-8) sd = 1e-8;
    smean[t] = (float)m;
    srstd[t] = (float)(1.0 / sd);
  }
}

// ---------------- local Dirichlet energy (2x unrolled gather: 8 edges in flight) ----------------
__global__ __launch_bounds__(256) void k_energy(const float* __restrict__ Xs,
                                                const int* __restrict__ cnt,
                                                const int* __restrict__ offs,
                                                const int* __restrict__ csr,
                                                float* __restrict__ R) {
  int wid = threadIdx.x >> 6, lane = threadIdx.x & 63;
  int node = blockIdx.x * 4 + wid;
  if (node >= Nn) return;
  int q4 = lane >> 4;
  int cg = (lane & 15) * 4;
  float4 xi = *(const float4*)(Xs + (size_t)node * 64 + cg);
  float num[4] = {0.f, 0.f, 0.f, 0.f}, den[4] = {0.f, 0.f, 0.f, 0.f};
  int j0 = offs[node], j1 = offs[node + 1];
  for (int j = j0; j < j1; j += 8) {
    int e1 = j + q4, e2 = j + 4 + q4;
    int r1 = csr[min(e1, j1 - 1)];
    int r2 = csr[min(e2, j1 - 1)];
    float m1 = (e1 < j1) ? 1.f : 0.f;
    float m2 = (e2 < j1) ? 1.f : 0.f;
    float4 x1 = *(const float4*)(Xs + (size_t)r1 * 64 + cg);
    float4 x2 = *(const float4*)(Xs + (size_t)r2 * 64 + cg);
    {
      float d0 = m1 * (xi.x - x1.x), d1 = m1 * (xi.y - x1.y),
            d2 = m1 * (xi.z - x1.z), d3 = m1 * (xi.w - x1.w);
      num[0] += d0 * d0; num[1] += d1 * d1; num[2] += d2 * d2; num[3] += d3 * d3;
      float s0 = m1 * x1.x, s1 = m1 * x1.y, s2 = m1 * x1.z, s3 = m1 * x1.w;
      den[0] += s0 * s0; den[1] += s1 * s1; den[2] += s2 * s2; den[3] += s3 * s3;
    }
    {
      float d0 = m2 * (xi.x - x2.x), d1 = m2 * (xi.y - x2.y),
            d2 = m2 * (xi.z - x2.z), d3 = m2 * (xi.w - x2.w);
      num[0] += d0 * d0; num[1] += d1 * d1; num[2] += d2 * d2; num[3] += d3 * d3;
      float s0 = m2 * x2.x, s1 = m2 * x2.y, s2 = m2 * x2.z, s3 = m2 * x2.w;
      den[0] += s0 * s0; den[1] += s1 * s1; den[2] += s2 * s2; den[3] += s3 * s3;
    }
  }
  #pragma unroll
  for (int c = 0; c < 4; c++) {
    num[c] += __shfl_xor(num[c], 32); num[c] += __shfl_xor(num[c], 16);
    den[c] += __shfl_xor(den[c], 32); den[c] += __shfl_xor(den[c], 16);
  }
  if (q4 == 0) {
    float degf = (float)cnt[node];
    float4 o;
    o.x = num[0] / (den[0] + degf * xi.x * xi.x + 1e-8f);
    o.y = num[1] / (den[1] + degf * xi.y * xi.y + 1e-8f);
    o.z = num[2] / (den[2] + degf * xi.z * xi.z + 1e-8f);
    o.w = num[3] / (den[3] + degf * xi.w * xi.w + 1e-8f);
    *(float4*)(R + (size_t)node * 64 + cg) = o;
  }
}

// ---------------- gate MLP + Z (in-place R -> Z, fp32) ----------------
__global__ __launch_bounds__(256) void k_gate(const float* __restrict__ feat,
                                              const double* __restrict__ accF,
                                              const double* __restrict__ accR,
                                              const float* __restrict__ w1, const float* __restrict__ b1,
                                              const float* __restrict__ w2, const float* __restrict__ b2,
                                              float* __restrict__ RZ) {
  __shared__ float sw1[1024], sw2[1024], sb1[16], sb2[64], sfm[64], sfr[64], srm[64], srr[64];
  for (int i = threadIdx.x; i < 1024; i += 256) { sw1[i] = w1[i]; sw2[i] = w2[i]; }
  if (threadIdx.x < 16) sb1[threadIdx.x] = b1[threadIdx.x];
  if (threadIdx.x < 64) sb2[threadIdx.x] = b2[threadIdx.x];
  stats_final_sh(accF, sfm, sfr, threadIdx.x);
  stats_final_sh(accR, srm, srr, threadIdx.x);
  __syncthreads();
  int node = blockIdx.x * 256 + threadIdx.x;
  if (node >= Nn) return;
  float xn[64];
  const float4* fx = (const float4*)(feat + (size_t)node * 64);
  for (int q = 0; q < 16; q++) {
    float4 v = fx[q];
    xn[q * 4 + 0] = (v.x - sfm[q * 4 + 0]) * sfr[q * 4 + 0];
    xn[q * 4 + 1] = (v.y - sfm[q * 4 + 1]) * sfr[q * 4 + 1];
    xn[q * 4 + 2] = (v.z - sfm[q * 4 + 2]) * sfr[q * 4 + 2];
    xn[q * 4 + 3] = (v.w - sfm[q * 4 + 3]) * sfr[q * 4 + 3];
  }
  float hid[16];
  #pragma unroll
  for (int h = 0; h < 16; h++) {
    float a = sb1[h];
    #pragma unroll
    for (int k = 0; k < 64; k++) a += xn[k] * sw1[k * 16 + h];
    hid[h] = fmaxf(a, 0.f);
  }
  float4* row = (float4*)(RZ + (size_t)node * 64);
  for (int q = 0; q < 16; q++) {
    float4 rv = row[q];
    float Rv[4] = {rv.x, rv.y, rv.z, rv.w};
    float zo[4];
    #pragma unroll
    for (int j = 0; j < 4; j++) {
      int o = q * 4 + j;
      float a = sb2[o];
      #pragma unroll
      for (int h = 0; h < 16; h++) a += hid[h] * sw2[h * 64 + o];
      float g = 1.f / (1.f + expf(-a));
      float Rn = (Rv[j] - srm[o]) * srr[o];
      float Rf = (2.f - Rv[j] - srm[o]) * srr[o];
      zo[j] = g * Rn + (1.f - g) * Rf;
    }
    row[q] = make_float4(zo[0], zo[1], zo[2], zo[3]);
  }
}

// ---------------- attn MLP + h0 = en*attn (Z fp32 -> H0 bf16, coalesced store) ----------------
__global__ __launch_bounds__(256) void k_attn(const double* __restrict__ accZ,
                                              const float* __restrict__ w1, const float* __restrict__ b1,
                                              const float* __restrict__ w2, const float* __restrict__ b2,
                                              const float* __restrict__ Zf,
                                              unsigned short* __restrict__ Hh) {
  __shared__ float sw1[1024], sw2[1024], sb1[16], sb2[64], szm[64], szr[64];
  __shared__ unsigned short sout[256][72];
  for (int i = threadIdx.x; i < 1024; i += 256) { sw1[i] = w1[i]; sw2[i] = w2[i]; }
  if (threadIdx.x < 16) sb1[threadIdx.x] = b1[threadIdx.x];
  if (threadIdx.x < 64) sb2[threadIdx.x] = b2[threadIdx.x];
  stats_final_sh(accZ, szm, szr, threadIdx.x);
  __syncthreads();
  int node0 = blockIdx.x * 256;
  int node = node0 + threadIdx.x;
  if (node < Nn) {
    float en[64];
    const float4* row = (const float4*)(Zf + (size_t)node * 64);
    for (int q = 0; q < 16; q++) {
      float4 v = row[q];
      en[q * 4 + 0] = (v.x - szm[q * 4 + 0]) * szr[q * 4 + 0];
      en[q * 4 + 1] = (v.y - szm[q * 4 + 1]) * szr[q * 4 + 1];
      en[q * 4 + 2] = (v.z - szm[q * 4 + 2]) * szr[q * 4 + 2];
      en[q * 4 + 3] = (v.w - szm[q * 4 + 3]) * szr[q * 4 + 3];
    }
    float hid[16];
    #pragma unroll
    for (int h = 0; h < 16; h++) {
      float a = sb1[h];
      #pragma unroll
      for (int k = 0; k < 64; k++) a += en[k] * sw1[k * 16 + h];
      hid[h] = fmaxf(a, 0.f);
    }
    for (int q = 0; q < 16; q++) {
      #pragma unroll
      for (int j = 0; j < 4; j++) {
        int o = q * 4 + j;
        float a = sb2[o];
        #pragma unroll
        for (int h = 0; h < 16; h++) a += hid[h] * sw2[h * 64 + o];
        float att = 1.f / (1.f + expf(-a));
        sout[threadIdx.x][o] = f2bf_rtn(en[o] * att);
      }
    }
  }
  __syncthreads();
  int nval = (min(Nn - node0, 256)) * 64;
  for (int base = 0; base < 16384; base += 2048) {
    int i = base + threadIdx.x * 8;
    if (i < nval) {
      int r = i >> 6, c = i & 63;
      *(short8*)(Hh + (size_t)node0 * 64 + i) = *(const short8*)&sout[r][c];
    }
  }
}

// ---------------- neighbor-mean pulls ----------------
__global__ __launch_bounds__(256) void k_pull64b(const unsigned short* __restrict__ Xh,
                                                 const int* __restrict__ cnt,
                                                 const int* __restrict__ offs,
                                                 const int* __restrict__ csr,
                                                 unsigned short* __restrict__ Oh) {
  int wid = threadIdx.x >> 6, lane = threadIdx.x & 63;
  int node = blockIdx.x * 4 + wid;
  if (node >= Nn) return;
  int o8 = lane >> 3;
  int cg = (lane & 7) * 8;
  float s[8] = {0.f, 0.f, 0.f, 0.f, 0.f, 0.f, 0.f, 0.f};
  int j0 = offs[node], j1 = offs[node + 1];
  for (int j = j0; j < j1; j += 8) {
    int e = j + o8;
    if (e < j1) {
      short8 v = *(const short8*)(Xh + (size_t)csr[e] * 64 + cg);
      #pragma unroll
      for (int q = 0; q < 8; q++) s[q] += bf2f((unsigned short)v[q]);
    }
  }
  #pragma unroll
  for (int q = 0; q < 8; q++) {
    s[q] += __shfl_xor(s[q], 32);
    s[q] += __shfl_xor(s[q], 16);
    s[q] += __shfl_xor(s[q], 8);
  }
  if (o8 == 0) {
    float inv = 1.f / fmaxf((float)cnt[node], 1.f);
    short8 o;
    #pragma unroll
    for (int q = 0; q < 8; q++) o[q] = (short)f2bf_rtn(s[q] * inv);
    *(short8*)(Oh + (size_t)node * 64 + cg) = o;
  }
}

// 256-wide bf16: 32 lanes/row, 2x unrolled -> 4 edges in flight.
__global__ __launch_bounds__(256) void k_pull256b(const unsigned short* __restrict__ Xh,
                                                  const int* __restrict__ cnt,
                                                  const int* __restrict__ offs,
                                                  const int* __restrict__ csr,
                                                  unsigned short* __restrict__ Oh) {
  int wid = threadIdx.x >> 6, lane = threadIdx.x & 63;
  int node = blockIdx.x * 4 + wid;
  if (node >= Nn) return;
  int half = lane >> 5;
  int cg = (lane & 31) * 8;
  float s[8] = {0.f, 0.f, 0.f, 0.f, 0.f, 0.f, 0.f, 0.f};
  int j0 = offs[node], j1 = offs[node + 1];
  for (int j = j0; j < j1; j += 4) {
    int e1 = j + half, e2 = j + 2 + half;
    int r1 = csr[min(e1, j1 - 1)];
    int r2 = csr[min(e2, j1 - 1)];
    float m1 = (e1 < j1) ? 1.f : 0.f;
    float m2 = (e2 < j1) ? 1.f : 0.f;
    short8 v1 = *(const short8*)(Xh + (size_t)r1 * 256 + cg);
    short8 v2 = *(const short8*)(Xh + (size_t)r2 * 256 + cg);
    #pragma unroll
    for (int q = 0; q < 8; q++) s[q] += m1 * bf2f((unsigned short)v1[q]);
    #pragma unroll
    for (int q = 0; q < 8; q++) s[q] += m2 * bf2f((unsigned short)v2[q]);
  }
  #pragma unroll
  for (int q = 0; q < 8; q++) s[q] += __shfl_xor(s[q], 32);
  if (half == 0) {
    float inv = 1.f / fmaxf((float)cnt[node], 1.f);
    short8 o;
    #pragma unroll
    for (int q = 0; q < 8; q++) o[q] = (short)f2bf_rtn(s[q] * inv);
    *(short8*)(Oh + (size_t)node * 256 + cg) = o;
  }
}

// P3 gather: bf16 [N][128] in, fp32 [N][128] out; 16 lanes/row, 2x unrolled -> 8 edges in flight.
__global__ __launch_bounds__(256) void k_pullh(const unsigned short* __restrict__ P,
                                               const int* __restrict__ cnt,
                                               const int* __restrict__ offs,
                                               const int* __restrict__ csr,
                                               float* __restrict__ AG) {
  int wid = threadIdx.x >> 6, lane = threadIdx.x & 63;
  int node = blockIdx.x * 4 + wid;
  if (node >= Nn) return;
  int q4 = lane >> 4;
  int cg = (lane & 15) * 8;
  float s[8] = {0.f, 0.f, 0.f, 0.f, 0.f, 0.f, 0.f, 0.f};
  int j0 = offs[node], j1 = offs[node + 1];
  for (int j = j0; j < j1; j += 8) {
    int e1 = j + q4, e2 = j + 4 + q4;
    int r1 = csr[min(e1, j1 - 1)];
    int r2 = csr[min(e2, j1 - 1)];
    float m1 = (e1 < j1) ? 1.f : 0.f;
    float m2 = (e2 < j1) ? 1.f : 0.f;
    short8 v1 = *(const short8*)(P + (size_t)r1 * 128 + cg);
    short8 v2 = *(const short8*)(P + (size_t)r2 * 128 + cg);
    #pragma unroll
    for (int q = 0; q < 8; q++) s[q] += m1 * bf2f((unsigned short)v1[q]);
    #pragma unroll
    for (int q = 0; q < 8; q++) s[q] += m2 * bf2f((unsigned short)v2[q]);
  }
  #pragma unroll
  for (int q = 0; q < 8; q++) {
    s[q] += __shfl_xor(s[q], 32);
    s[q] += __shfl_xor(s[q], 16);
  }
  if (q4 == 0) {
    float inv = 1.f / fmaxf((float)cnt[node], 1.f);
    float* dst = AG + (size_t)node * 128 + cg;
    *(float4*)dst = make_float4(s[0] * inv, s[1] * inv, s[2] * inv, s[3] * inv);
    *(float4*)(dst + 4) = make_float4(s[4] * inv, s[5] * inv, s[6] * inv, s[7] * inv);
  }
}

// ---------------- weight prep ----------------
__global__ void k_prep(const float* __restrict__ W, int K, int N,
                       unsigned short* __restrict__ Hi, unsigned short* __restrict__ Lo) {
  int idx = blockIdx.x * 256 + threadIdx.x;
  if (idx >= K * N) return;
  int k = idx / N, n = idx - k * N;
  float x = W[idx];
  unsigned short h = f2bf_rtn(x);
  Hi[(size_t)n * K + k] = h;
  Lo[(size_t)n * K + k] = f2bf_rtn(x - bf2f(h));
}

__global__ void k_bias_pad(const float* __restrict__ b, float* __restrict__ out) {
  int i = threadIdx.x;
  out[i] = (i < 128) ? b[i] : 0.f;
}

// ---------------- bf16-A x split-bf16-B MFMA GEMM, BM=64 BN=256 BK=32, dbuf + LDS epilogue ----------------
template <int PASSES, bool RELU, bool SPLITOUT>
__global__ __launch_bounds__(256, 2) void k_gemm(
    const unsigned short* __restrict__ A1,
    const unsigned short* __restrict__ B1h, const unsigned short* __restrict__ B1l,
    const unsigned short* __restrict__ A2,
    const unsigned short* __restrict__ B2h, const unsigned short* __restrict__ B2l,
    const float* __restrict__ bias,
    unsigned short* __restrict__ Cb, float* __restrict__ S3, unsigned short* __restrict__ P3,
    int K) {
  __shared__ __align__(16) unsigned short smem[36864];   // 72KB
  const int tid = threadIdx.x;
  const int lane = tid & 63;
  const int wid = tid >> 6;
  const int l15 = lane & 15, l4 = lane >> 4;
  const int wm = (wid >> 1) * 32;
  const int wn2 = (wid & 1) * 128;
  const int row0 = blockIdx.x * 64;
  const int srow = lane >> 2;
  const int sg = ((lane & 3) ^ ((lane >> 3) & 3)) * 8;
  const int gsw = (l4 ^ ((l15 >> 1) & 3)) * 8;

  const int ktiles = K >> 5;
  const int nt = PASSES * ktiles;

  auto Ash = [&](int b) { return smem + b * 2048; };
  auto Bsh = [&](int b) { return smem + 4096 + b * 8192; };
  auto Bsl = [&](int b) { return smem + 20480 + b * 8192; };

  auto stage = [&](int t, int b) {
    int pass = (PASSES == 2 && t >= ktiles) ? 1 : 0;
    int k0 = (t - pass * ktiles) << 5;
    const unsigned short* gA = pass ? A2 : A1;
    const unsigned short* gBh = pass ? B2h : B1h;
    const unsigned short* gBl = pass ? B2l : B1l;
    #pragma unroll
    for (int cc = 0; cc < 9; ++cc) {
      int c = wid * 9 + cc;
      unsigned short* lb;
      const unsigned short* gb;
      int grow;
      if (c < 4)       { lb = Ash(b) + c * 512;               gb = gA;  grow = row0 + c * 16 + srow; }
      else if (c < 20) { int q = c - 4;  lb = Bsh(b) + q * 512; gb = gBh; grow = q * 16 + srow; }
      else             { int q = c - 20; lb = Bsl(b) + q * 512; gb = gBl; grow = q * 16 + srow; }
      __builtin_amdgcn_global_load_lds(
          (const __attribute__((address_space(1))) void*)(gb + (size_t)grow * K + k0 + sg),
          (__attribute__((address_space(3))) void*)lb, 16, 0, 0);
    }
  };

  f32x4 acc[2][8];
  #pragma unroll
  for (int s = 0; s < 2; ++s)
    #pragma unroll
    for (int t = 0; t < 8; ++t) acc[s][t] = (f32x4)0.0f;

  stage(0, 0);
  __syncthreads();
  for (int t = 0; t < nt; ++t) {
    int buf = t & 1;
    if (t + 1 < nt) stage(t + 1, buf ^ 1);
    short8 af[2];
    #pragma unroll
    for (int s = 0; s < 2; ++s)
      af[s] = *(const short8*)&Ash(buf)[(wm + s * 16 + l15) * 32 + gsw];
    #pragma unroll
    for (int tt = 0; tt < 8; ++tt) {
      short8 b = *(const short8*)&Bsh(buf)[(wn2 + tt * 16 + l15) * 32 + gsw];
      #pragma unroll
      for (int s = 0; s < 2; ++s)
        acc[s][tt] = __builtin_amdgcn_mfma_f32_16x16x32_bf16(af[s], b, acc[s][tt], 0, 0, 0);
    }
    #pragma unroll
    for (int tt = 0; tt < 8; ++tt) {
      short8 b = *(const short8*)&Bsl(buf)[(wn2 + tt * 16 + l15) * 32 + gsw];
      #pragma unroll
      for (int s = 0; s < 2; ++s)
        acc[s][tt] = __builtin_amdgcn_mfma_f32_16x16x32_bf16(af[s], b, acc[s][tt], 0, 0, 0);
    }
    __syncthreads();
  }

  // ---- epilogue: stage bf16 output in LDS, then coalesced short8 streams ----
  if (!SPLITOUT) {
    unsigned short* Cs = smem;   // 64x256 bf16 = 32KB
    #pragma unroll
    for (int tt = 0; tt < 8; ++tt) {
      int col = wn2 + tt * 16 + l15;
      float bv = bias[col];
      #pragma unroll
      for (int s = 0; s < 2; ++s) {
        int r = wm + s * 16 + l4 * 4;
        #pragma unroll
        for (int j = 0; j < 4; ++j) {
          float v = acc[s][tt][j] + bv;
          if (RELU) v = fmaxf(v, 0.f);
          Cs[(r + j) * 256 + col] = f2bf_rtn(v);
        }
      }
    }
    __syncthreads();
    #pragma unroll
    for (int it = 0; it < 8; ++it) {
      int ch = it * 256 + tid;
      int row = row0 + (ch >> 5);
      if (row < Nn)
        *(short8*)(Cb + (size_t)row * 256 + (ch & 31) * 8) = *(const short8*)&Cs[ch * 8];
    }
  } else {
    unsigned short* Ps = smem;   // 64x128 bf16 = 16KB
    #pragma unroll
    for (int tt = 0; tt < 8; ++tt) {
      int col = wn2 + tt * 16 + l15;
      float bv = bias[col];
      #pragma unroll
      for (int s = 0; s < 2; ++s) {
        int r = wm + s * 16 + l4 * 4;
        #pragma unroll
        for (int j = 0; j < 4; ++j) {
          float v = acc[s][tt][j] + bv;
          if (RELU) v = fmaxf(v, 0.f);
          int row = row0 + r + j;
          if (wn2 == 0) {
            if (row < Nn) S3[(size_t)row * 128 + col] = v;
          } else {
            Ps[(r + j) * 128 + (col - 128)] = f2bf_rtn(v);
          }
        }
      }
    }
    __syncthreads();
    #pragma unroll
    for (int it = 0; it < 4; ++it) {
      int ch = it * 256 + tid;
      int row = row0 + (ch >> 4);
      if (row < Nn)
        *(short8*)(P3 + (size_t)row * 128 + (ch & 15) * 8) = *(const short8*)&Ps[ch * 8];
    }
  }
}

// ---------------- final classifier: h3 = relu(S3 + AG3); out = h3 @ clw + clb ----------------
// LDS weight reads are wave-uniform (broadcast, conflict-free).
__global__ __launch_bounds__(256) void k_cls2(const float* __restrict__ S3,
                                              const float* __restrict__ AG3,
                                              const float* __restrict__ W,
                                              const float* __restrict__ B,
                                              float* __restrict__ out) {
  __shared__ float sw[1024];
  __shared__ float sb[8];
  for (int i = threadIdx.x; i < 1024; i += 256) sw[i] = W[i];
  if (threadIdx.x < 8) sb[threadIdx.x] = B[threadIdx.x];
  __syncthreads();
  int node = blockIdx.x * 256 + threadIdx.x;
  if (node >= Nn) return;
  float acc[8];
  #pragma unroll
  for (int o = 0; o < 8; o++) acc[o] = sb[o];
  const float4* s4 = (const float4*)(S3 + (size_t)node * 128);
  const float4* a4 = (const float4*)(AG3 + (size_t)node * 128);
  for (int k4 = 0; k4 < 32; k4++) {
    float4 sv = s4[k4];
    float4 av = a4[k4];
    float vv[4] = {fmaxf(sv.x + av.x, 0.f), fmaxf(sv.y + av.y, 0.f),
                   fmaxf(sv.z + av.z, 0.f), fmaxf(sv.w + av.w, 0.f)};
    #pragma unroll
    for (int j = 0; j < 4; j++) {
      int k = k4 * 4 + j;
      #pragma unroll
      for (int o = 0; o < 8; o++) acc[o] += vv[j] * sw[k * 8 + o];
    }
  }
  float4* orow = (float4*)(out + (size_t)node * 8);
  orow[0] = make_float4(acc[0], acc[1], acc[2], acc[3]);
  orow[1] = make_float4(acc[4], acc[5], acc[6], acc[7]);
}

extern "C" void kernel_launch(void* const* d_in, const int* in_sizes, int n_in,
                              void* d_out, int out_size, void* d_ws, size_t ws_size,
                              hipStream_t stream) {
  (void)in_sizes; (void)n_in; (void)out_size; (void)ws_size;
  const float* feat = (const float*)d_in[0];
  const int* eidx = (const int*)d_in[1];
  const int* esrc = eidx;
  const int* edst = eidx + Ee;
  const float* gw1 = (const float*)d_in[2];  const float* gb1 = (const float*)d_in[3];
  const float* gw2 = (const float*)d_in[4];  const float* gb2 = (const float*)d_in[5];
  const float* aw1 = (const float*)d_in[6];  const float* ab1 = (const float*)d_in[7];
  const float* aw2 = (const float*)d_in[8];  const float* ab2 = (const float*)d_in[9];
  const float* c1ws = (const float*)d_in[10]; const float* c1wn = (const float*)d_in[11]; const float* c1b = (const float*)d_in[12];
  const float* c2ws = (const float*)d_in[13]; const float* c2wn = (const float*)d_in[14]; const float* c2b = (const float*)d_in[15];
  const float* c3ws = (const float*)d_in[16]; const float* c3wn = (const float*)d_in[17]; const float* c3b = (const float*)d_in[18];
  const float* clw = (const float*)d_in[19];  const float* clb = (const float*)d_in[20];
  float* out = (float*)d_out;

  char* ws = (char*)d_ws;
  size_t off = 0;
  auto alloc = [&](size_t b) -> char* {
    char* p = ws + off;
    off = (off + b + 255) & ~(size_t)255;
    return p;
  };
  int* cnt = (int*)alloc(Nn * 4);
  int* cur = (int*)alloc(Nn * 4);
  double* accF = (double*)alloc(128 * 8);
  double* accR = (double*)alloc(128 * 8);
  double* accZ = (double*)alloc(128 * 8);
  size_t zbytes = off;  // region above must be zeroed
  int* offs = (int*)alloc((size_t)(Nn + 1) * 4);
  int* csr = (int*)alloc((size_t)Ee * 4);
  int* bsum = (int*)alloc(NBLK * 4);
  int* bbase = (int*)alloc(NBLK * 4);
  float* dinv = (float*)alloc(Nn * 4);
  unsigned short* B1sh = (unsigned short*)alloc(256 * 64 * 2);
  unsigned short* B1sl = (unsigned short*)alloc(256 * 64 * 2);
  unsigned short* B1nh = (unsigned short*)alloc(256 * 64 * 2);
  unsigned short* B1nl = (unsigned short*)alloc(256 * 64 * 2);
  unsigned short* B2sh = (unsigned short*)alloc(256 * 256 * 2);
  unsigned short* B2sl = (unsigned short*)alloc(256 * 256 * 2);
  unsigned short* B2nh = (unsigned short*)alloc(256 * 256 * 2);
  unsigned short* B2nl = (unsigned short*)alloc(256 * 256 * 2);
  unsigned short* B3h = (unsigned short*)alloc(256 * 256 * 2);
  unsigned short* B3l = (unsigned short*)alloc(256 * 256 * 2);
  float* b3p = (float*)alloc(256 * 4);
  float* Xs = (float*)alloc((size_t)Nn * 64 * 4);
  float* Zf = (float*)alloc((size_t)Nn * 64 * 4);
  unsigned short* H0h = (unsigned short*)alloc((size_t)Nn * 64 * 2);
  unsigned short* AG0 = (unsigned short*)alloc((size_t)Nn * 64 * 2);
  unsigned short* H1h = (unsigned short*)alloc((size_t)Nn * 256 * 2);
  unsigned short* AG1 = (unsigned short*)alloc((size_t)Nn * 256 * 2);
  unsigned short* H2h = (unsigned short*)alloc((size_t)Nn * 256 * 2);
  alloc(65536);  // guard for OOB A-row staging
  float* S3f = (float*)Zf;            // alias (Zf dead after k_attn)
  unsigned short* P3h = AG1;          // alias (AG1 dead after GEMM2)
  float* AG3 = (float*)H1h;           // alias (H1 dead after GEMM2)

  hipMemsetAsync(d_ws, 0, zbytes, stream);

  hipLaunchKernelGGL(k_prep, dim3(64), dim3(256), 0, stream, c1ws, 64, 256, B1sh, B1sl);
  hipLaunchKernelGGL(k_prep, dim3(64), dim3(256), 0, stream, c1wn, 64, 256, B1nh, B1nl);
  hipLaunchKernelGGL(k_prep, dim3(256), dim3(256), 0, stream, c2ws, 256, 256, B2sh, B2sl);
  hipLaunchKernelGGL(k_prep, dim3(256), dim3(256), 0, stream, c2wn, 256, 256, B2nh, B2nl);
  hipLaunchKernelGGL(k_prep, dim3(128), dim3(256), 0, stream, c3ws, 256, 128, B3h, B3l);
  hipLaunchKernelGGL(k_prep, dim3(128), dim3(256), 0, stream, c3wn, 256, 128,
                     B3h + 128 * 256, B3l + 128 * 256);
  hipLaunchKernelGGL(k_bias_pad, dim3(1), dim3(256), 0, stream, c3b, b3p);

  int eb = (Ee + 255) / 256;
  hipLaunchKernelGGL(k_count, dim3(eb), dim3(256), 0, stream, edst, cnt);
  hipLaunchKernelGGL(k_bsum, dim3(NBLK), dim3(256), 0, stream, cnt, bsum);
  hipLaunchKernelGGL(k_bscan, dim3(1), dim3(256), 0, stream, bsum, bbase, offs);
  hipLaunchKernelGGL(k_offsets, dim3(NBLK), dim3(256), 0, stream, cnt, bbase, offs, dinv);
  hipLaunchKernelGGL(k_scatter, dim3(eb), dim3(256), 0, stream, esrc, edst, offs, cur, csr);

  hipLaunchKernelGGL((k_stats<true>), dim3(196), dim3(256), 0, stream, feat, accF, dinv, Xs);

  hipLaunchKernelGGL(k_energy, dim3((Nn + 3) / 4), dim3(256), 0, stream,
                     Xs, cnt, offs, csr, Zf);
  hipLaunchKernelGGL((k_stats<false>), dim3(196), dim3(256), 0, stream, Zf, accR,
                     (const float*)nullptr, (float*)nullptr);

  hipLaunchKernelGGL(k_gate, dim3((Nn + 255) / 256), dim3(256), 0, stream,
                     feat, accF, accR, gw1, gb1, gw2, gb2, Zf);
  hipLaunchKernelGGL((k_stats<false>), dim3(196), dim3(256), 0, stream, Zf, accZ,
                     (const float*)nullptr, (float*)nullptr);

  hipLaunchKernelGGL(k_attn, dim3(196), dim3(256), 0, stream,
                     accZ, aw1, ab1, aw2, ab2, Zf, H0h);

  hipLaunchKernelGGL(k_pull64b, dim3((Nn + 3) / 4), dim3(256), 0, stream,
                     H0h, cnt, offs, csr, AG0);
  hipLaunchKernelGGL((k_gemm<2, true, false>), dim3(782), dim3(256), 0, stream,
                     H0h, B1sh, B1sl, AG0, B1nh, B1nl, c1b,
                     H1h, (float*)nullptr, (unsigned short*)nullptr, 64);
  hipLaunchKernelGGL(k_pull256b, dim3((Nn + 3) / 4), dim3(256), 0, stream,
                     H1h, cnt, offs, csr, AG1);
  hipLaunchKernelGGL((k_gemm<2, true, false>), dim3(782), dim3(256), 0, stream,
                     H1h, B2sh, B2sl, AG1, B2nh, B2nl, c2b,
                     H2h, (float*)nullptr, (unsigned short*)nullptr, 256);
  hipLaunchKernelGGL((k_gemm<1, false, true>), dim3(782), dim3(256), 0, stream,
                     H2h, B3h, B3l,
                     (unsigned short*)nullptr, (unsigned short*)nullptr, (unsigned short*)nullptr,
                     b3p, (unsigned short*)nullptr, S3f, P3h, 256);
  hipLaunchKernelGGL(k_pullh, dim3((Nn + 3) / 4), dim3(256), 0, stream,
                     P3h, cnt, offs, csr, AG3);
  hipLaunchKernelGGL(k_cls2, dim3((Nn + 255) / 256), dim3(256), 0, stream,
                     S3f, AG3, clw, clb, out);
}

// Round 13
// 529.447 us; speedup vs baseline: 1.2669x; 1.0810x over previous
//
#include <hip/hip_runtime.h>
#include <math.h>

constexpr int Nn = 50000;
constexpr int Ee = 800000;
constexpr int NBLK = (Nn + 255) / 256;  // 196

typedef __attribute__((ext_vector_type(8))) short short8;
typedef __attribute__((ext_vector_type(4))) float f32x4;

__device__ inline unsigned short f2bf_rtn(float f) {
  union { float f; unsigned u; } v; v.f = f;
  unsigned r = v.u + 0x7FFFu + ((v.u >> 16) & 1u);
  return (unsigned short)(r >> 16);
}
__device__ inline float bf2f(unsigned short h) {
  union { unsigned u; float f; } v; v.u = ((unsigned)h) << 16;
  return v.f;
}

// ---------------- CSR build ----------------
__global__ void k_count(const int* __restrict__ dst, int* __restrict__ cnt) {
  int e = blockIdx.x * 256 + threadIdx.x;
  if (e < Ee) atomicAdd(&cnt[dst[e]], 1);
}

__global__ __launch_bounds__(256) void k_bsum(const int* __restrict__ cnt, int* __restrict__ bsum) {
  __shared__ int sh[256];
  int i = blockIdx.x * 256 + threadIdx.x;
  int v = (i < Nn) ? cnt[i] : 0;
  sh[threadIdx.x] = v;
  __syncthreads();
  #pragma unroll
  for (int off = 128; off > 0; off >>= 1) {
    if (threadIdx.x < off) sh[threadIdx.x] += sh[threadIdx.x + off];
    __syncthreads();
  }
  if (threadIdx.x == 0) bsum[blockIdx.x] = sh[0];
}

__global__ __launch_bounds__(256) void k_bscan(const int* __restrict__ bsum,
                                               int* __restrict__ bbase, int* __restrict__ offs) {
  __shared__ int sh[256];
  int t = threadIdx.x;
  int v = (t < NBLK) ? bsum[t] : 0;
  sh[t] = v;
  __syncthreads();
  #pragma unroll
  for (int off = 1; off < 256; off <<= 1) {
    int u = (t >= off) ? sh[t - off] : 0;
    __syncthreads();
    sh[t] += u;
    __syncthreads();
  }
  if (t < NBLK) bbase[t] = sh[t] - v;
  if (t == 0) offs[Nn] = Ee;
}

__global__ __launch_bounds__(256) void k_offsets(const int* __restrict__ cnt,
                                                 const int* __restrict__ bbase,
                                                 int* __restrict__ offs, float* __restrict__ dinv) {
  __shared__ int sh[256];
  int i = blockIdx.x * 256 + threadIdx.x;
  int t = threadIdx.x;
  int v = (i < Nn) ? cnt[i] : 0;
  sh[t] = v;
  __syncthreads();
  #pragma unroll
  for (int off = 1; off < 256; off <<= 1) {
    int u = (t >= off) ? sh[t - off] : 0;
    __syncthreads();
    sh[t] += u;
    __syncthreads();
  }
  if (i < Nn) {
    offs[i] = bbase[blockIdx.x] + sh[t] - v;
    dinv[i] = rsqrtf(fmaxf((float)v, 1e-12f));
  }
}

__global__ void k_scatter(const int* __restrict__ src, const int* __restrict__ dst,
                          const int* __restrict__ offs, int* __restrict__ cur,
                          int* __restrict__ csr) {
  int e = blockIdx.x * 256 + threadIdx.x;
  if (e < Ee) {
    int d = dst[e];
    int p = offs[d] + atomicAdd(&cur[d], 1);
    csr[p] = src[e];
  }
}

// ---------------- column stats (64-wide, ddof=1); statsx also emits Xs = feat*dinv ----------------
template <bool EMITXS>
__global__ __launch_bounds__(256) void k_stats(const float* __restrict__ X, double* __restrict__ acc,
                                               const float* __restrict__ dinv, float* __restrict__ Xs) {
  int col = threadIdx.x & 63, rs_ = threadIdx.x >> 6;
  int row0 = blockIdx.x * 256;
  int rend = min(row0 + 256, Nn);
  double s = 0.0, ss = 0.0;
  for (int r = row0 + rs_; r < rend; r += 4) {
    float v = X[(size_t)r * 64 + col];
    if (EMITXS) Xs[(size_t)r * 64 + col] = v * dinv[r];
    s += v; ss += (double)v * v;
  }
  __shared__ double sh[512];
  sh[threadIdx.x] = s; sh[256 + threadIdx.x] = ss;
  __syncthreads();
  if (rs_ == 0) {
    s = sh[col] + sh[col + 64] + sh[col + 128] + sh[col + 192];
    ss = sh[256 + col] + sh[256 + col + 64] + sh[256 + col + 128] + sh[256 + col + 192];
    atomicAdd(&acc[col], s);
    atomicAdd(&acc[64 + col], ss);
  }
}

__device__ inline void stats_final_sh(const double* acc, float* smean, float* srstd, int t) {
  if (t < 64) {
    double s = acc[t], ss = acc[64 + t];
    double m = s / (double)Nn;
    double var = (ss - s * s / (double)Nn) / (double)(Nn - 1);
    double sd = sqrt(var > 0.0 ? var : 0.0);
    if (sd < 1e-8) sd = 1e-8;
    smean[t] = (float)m;
    srstd[t] = (float)(1.0 / sd);
  }
}

// ---------------- local Dirichlet energy (2x unrolled gather: 8 edges in flight) ----------------
__global__ __launch_bounds__(256) void k_energy(const float* __restrict__ Xs,
                                                const int* __restrict__ cnt,
                                                const int* __restrict__ offs,
                                                const int* __restrict__ csr,
                                                float* __restrict__ R) {
  int wid = threadIdx.x >> 6, lane = threadIdx.x & 63;
  int node = blockIdx.x * 4 + wid;
  if (node >= Nn) return;
  int q4 = lane >> 4;
  int cg = (lane & 15) * 4;
  float4 xi = *(const float4*)(Xs + (size_t)node * 64 + cg);
  float num[4] = {0.f, 0.f, 0.f, 0.f}, den[4] = {0.f, 0.f, 0.f, 0.f};
  int j0 = offs[node], j1 = offs[node + 1];
  for (int j = j0; j < j1; j += 8) {
    int e1 = j + q4, e2 = j + 4 + q4;
    int r1 = csr[min(e1, j1 - 1)];
    int r2 = csr[min(e2, j1 - 1)];
    float m1 = (e1 < j1) ? 1.f : 0.f;
    float m2 = (e2 < j1) ? 1.f : 0.f;
    float4 x1 = *(const float4*)(Xs + (size_t)r1 * 64 + cg);
    float4 x2 = *(const float4*)(Xs + (size_t)r2 * 64 + cg);
    {
      float d0 = m1 * (xi.x - x1.x), d1 = m1 * (xi.y - x1.y),
            d2 = m1 * (xi.z - x1.z), d3 = m1 * (xi.w - x1.w);
      num[0] += d0 * d0; num[1] += d1 * d1; num[2] += d2 * d2; num[3] += d3 * d3;
      float s0 = m1 * x1.x, s1 = m1 * x1.y, s2 = m1 * x1.z, s3 = m1 * x1.w;
      den[0] += s0 * s0; den[1] += s1 * s1; den[2] += s2 * s2; den[3] += s3 * s3;
    }
    {
      float d0 = m2 * (xi.x - x2.x), d1 = m2 * (xi.y - x2.y),
            d2 = m2 * (xi.z - x2.z), d3 = m2 * (xi.w - x2.w);
      num[0] += d0 * d0; num[1] += d1 * d1; num[2] += d2 * d2; num[3] += d3 * d3;
      float s0 = m2 * x2.x, s1 = m2 * x2.y, s2 = m2 * x2.z, s3 = m2 * x2.w;
      den[0] += s0 * s0; den[1] += s1 * s1; den[2] += s2 * s2; den[3] += s3 * s3;
    }
  }
  #pragma unroll
  for (int c = 0; c < 4; c++) {
    num[c] += __shfl_xor(num[c], 32); num[c] += __shfl_xor(num[c], 16);
    den[c] += __shfl_xor(den[c], 32); den[c] += __shfl_xor(den[c], 16);
  }
  if (q4 == 0) {
    float degf = (float)cnt[node];
    float4 o;
    o.x = num[0] / (den[0] + degf * xi.x * xi.x + 1e-8f);
    o.y = num[1] / (den[1] + degf * xi.y * xi.y + 1e-8f);
    o.z = num[2] / (den[2] + degf * xi.z * xi.z + 1e-8f);
    o.w = num[3] / (den[3] + degf * xi.w * xi.w + 1e-8f);
    *(float4*)(R + (size_t)node * 64 + cg) = o;
  }
}

// ---------------- gate MLP + Z (in-place R -> Z, fp32) ----------------
__global__ __launch_bounds__(256) void k_gate(const float* __restrict__ feat,
                                              const double* __restrict__ accF,
                                              const double* __restrict__ accR,
                                              const float* __restrict__ w1, const float* __restrict__ b1,
                                              const float* __restrict__ w2, const float* __restrict__ b2,
                                              float* __restrict__ RZ) {
  __shared__ float sw1[1024], sw2[1024], sb1[16], sb2[64], sfm[64], sfr[64], srm[64], srr[64];
  for (int i = threadIdx.x; i < 1024; i += 256) { sw1[i] = w1[i]; sw2[i] = w2[i]; }
  if (threadIdx.x < 16) sb1[threadIdx.x] = b1[threadIdx.x];
  if (threadIdx.x < 64) sb2[threadIdx.x] = b2[threadIdx.x];
  stats_final_sh(accF, sfm, sfr, threadIdx.x);
  stats_final_sh(accR, srm, srr, threadIdx.x);
  __syncthreads();
  int node = blockIdx.x * 256 + threadIdx.x;
  if (node >= Nn) return;
  float xn[64];
  const float4* fx = (const float4*)(feat + (size_t)node * 64);
  for (int q = 0; q < 16; q++) {
    float4 v = fx[q];
    xn[q * 4 + 0] = (v.x - sfm[q * 4 + 0]) * sfr[q * 4 + 0];
    xn[q * 4 + 1] = (v.y - sfm[q * 4 + 1]) * sfr[q * 4 + 1];
    xn[q * 4 + 2] = (v.z - sfm[q * 4 + 2]) * sfr[q * 4 + 2];
    xn[q * 4 + 3] = (v.w - sfm[q * 4 + 3]) * sfr[q * 4 + 3];
  }
  float hid[16];
  #pragma unroll
  for (int h = 0; h < 16; h++) {
    float a = sb1[h];
    #pragma unroll
    for (int k = 0; k < 64; k++) a += xn[k] * sw1[k * 16 + h];
    hid[h] = fmaxf(a, 0.f);
  }
  float4* row = (float4*)(RZ + (size_t)node * 64);
  for (int q = 0; q < 16; q++) {
    float4 rv = row[q];
    float Rv[4] = {rv.x, rv.y, rv.z, rv.w};
    float zo[4];
    #pragma unroll
    for (int j = 0; j < 4; j++) {
      int o = q * 4 + j;
      float a = sb2[o];
      #pragma unroll
      for (int h = 0; h < 16; h++) a += hid[h] * sw2[h * 64 + o];
      float g = 1.f / (1.f + expf(-a));
      float Rn = (Rv[j] - srm[o]) * srr[o];
      float Rf = (2.f - Rv[j] - srm[o]) * srr[o];
      zo[j] = g * Rn + (1.f - g) * Rf;
    }
    row[q] = make_float4(zo[0], zo[1], zo[2], zo[3]);
  }
}

// ---------------- attn MLP + h0 = en*attn (Z fp32 -> H0 bf16, coalesced store) ----------------
__global__ __launch_bounds__(256) void k_attn(const double* __restrict__ accZ,
                                              const float* __restrict__ w1, const float* __restrict__ b1,
                                              const float* __restrict__ w2, const float* __restrict__ b2,
                                              const float* __restrict__ Zf,
                                              unsigned short* __restrict__ Hh) {
  __shared__ float sw1[1024], sw2[1024], sb1[16], sb2[64], szm[64], szr[64];
  __shared__ unsigned short sout[256][72];
  for (int i = threadIdx.x; i < 1024; i += 256) { sw1[i] = w1[i]; sw2[i] = w2[i]; }
  if (threadIdx.x < 16) sb1[threadIdx.x] = b1[threadIdx.x];
  if (threadIdx.x < 64) sb2[threadIdx.x] = b2[threadIdx.x];
  stats_final_sh(accZ, szm, szr, threadIdx.x);
  __syncthreads();
  int node0 = blockIdx.x * 256;
  int node = node0 + threadIdx.x;
  if (node < Nn) {
    float en[64];
    const float4* row = (const float4*)(Zf + (size_t)node * 64);
    for (int q = 0; q < 16; q++) {
      float4 v = row[q];
      en[q * 4 + 0] = (v.x - szm[q * 4 + 0]) * szr[q * 4 + 0];
      en[q * 4 + 1] = (v.y - szm[q * 4 + 1]) * szr[q * 4 + 1];
      en[q * 4 + 2] = (v.z - szm[q * 4 + 2]) * szr[q * 4 + 2];
      en[q * 4 + 3] = (v.w - szm[q * 4 + 3]) * szr[q * 4 + 3];
    }
    float hid[16];
    #pragma unroll
    for (int h = 0; h < 16; h++) {
      float a = sb1[h];
      #pragma unroll
      for (int k = 0; k < 64; k++) a += en[k] * sw1[k * 16 + h];
      hid[h] = fmaxf(a, 0.f);
    }
    for (int q = 0; q < 16; q++) {
      #pragma unroll
      for (int j = 0; j < 4; j++) {
        int o = q * 4 + j;
        float a = sb2[o];
        #pragma unroll
        for (int h = 0; h < 16; h++) a += hid[h] * sw2[h * 64 + o];
        float att = 1.f / (1.f + expf(-a));
        sout[threadIdx.x][o] = f2bf_rtn(en[o] * att);
      }
    }
  }
  __syncthreads();
  int nval = (min(Nn - node0, 256)) * 64;
  for (int base = 0; base < 16384; base += 2048) {
    int i = base + threadIdx.x * 8;
    if (i < nval) {
      int r = i >> 6, c = i & 63;
      *(short8*)(Hh + (size_t)node0 * 64 + i) = *(const short8*)&sout[r][c];
    }
  }
}

// ---------------- neighbor-mean pulls ----------------
__global__ __launch_bounds__(256) void k_pull64b(const unsigned short* __restrict__ Xh,
                                                 const int* __restrict__ cnt,
                                                 const int* __restrict__ offs,
                                                 const int* __restrict__ csr,
                                                 unsigned short* __restrict__ Oh) {
  int wid = threadIdx.x >> 6, lane = threadIdx.x & 63;
  int node = blockIdx.x * 4 + wid;
  if (node >= Nn) return;
  int o8 = lane >> 3;
  int cg = (lane & 7) * 8;
  float s[8] = {0.f, 0.f, 0.f, 0.f, 0.f, 0.f, 0.f, 0.f};
  int j0 = offs[node], j1 = offs[node + 1];
  for (int j = j0; j < j1; j += 8) {
    int e = j + o8;
    if (e < j1) {
      short8 v = *(const short8*)(Xh + (size_t)csr[e] * 64 + cg);
      #pragma unroll
      for (int q = 0; q < 8; q++) s[q] += bf2f((unsigned short)v[q]);
    }
  }
  #pragma unroll
  for (int q = 0; q < 8; q++) {
    s[q] += __shfl_xor(s[q], 32);
    s[q] += __shfl_xor(s[q], 16);
    s[q] += __shfl_xor(s[q], 8);
  }
  if (o8 == 0) {
    float inv = 1.f / fmaxf((float)cnt[node], 1.f);
    short8 o;
    #pragma unroll
    for (int q = 0; q < 8; q++) o[q] = (short)f2bf_rtn(s[q] * inv);
    *(short8*)(Oh + (size_t)node * 64 + cg) = o;
  }
}

// 256-wide bf16: 32 lanes/row, 2x unrolled -> 4 edges in flight.
__global__ __launch_bounds__(256) void k_pull256b(const unsigned short* __restrict__ Xh,
                                                  const int* __restrict__ cnt,
                                                  const int* __restrict__ offs,
                                                  const int* __restrict__ csr,
                                                  unsigned short* __restrict__ Oh) {
  int wid = threadIdx.x >> 6, lane = threadIdx.x & 63;
  int node = blockIdx.x * 4 + wid;
  if (node >= Nn) return;
  int half = lane >> 5;
  int cg = (lane & 31) * 8;
  float s[8] = {0.f, 0.f, 0.f, 0.f, 0.f, 0.f, 0.f, 0.f};
  int j0 = offs[node], j1 = offs[node + 1];
  for (int j = j0; j < j1; j += 4) {
    int e1 = j + half, e2 = j + 2 + half;
    int r1 = csr[min(e1, j1 - 1)];
    int r2 = csr[min(e2, j1 - 1)];
    float m1 = (e1 < j1) ? 1.f : 0.f;
    float m2 = (e2 < j1) ? 1.f : 0.f;
    short8 v1 = *(const short8*)(Xh + (size_t)r1 * 256 + cg);
    short8 v2 = *(const short8*)(Xh + (size_t)r2 * 256 + cg);
    #pragma unroll
    for (int q = 0; q < 8; q++) s[q] += m1 * bf2f((unsigned short)v1[q]);
    #pragma unroll
    for (int q = 0; q < 8; q++) s[q] += m2 * bf2f((unsigned short)v2[q]);
  }
  #pragma unroll
  for (int q = 0; q < 8; q++) s[q] += __shfl_xor(s[q], 32);
  if (half == 0) {
    float inv = 1.f / fmaxf((float)cnt[node], 1.f);
    short8 o;
    #pragma unroll
    for (int q = 0; q < 8; q++) o[q] = (short)f2bf_rtn(s[q] * inv);
    *(short8*)(Oh + (size_t)node * 256 + cg) = o;
  }
}

// P3 gather: bf16 [N][128] in, fp32 [N][128] out; 16 lanes/row, 2x unrolled -> 8 edges in flight.
__global__ __launch_bounds__(256) void k_pullh(const unsigned short* __restrict__ P,
                                               const int* __restrict__ cnt,
                                               const int* __restrict__ offs,
                                               const int* __restrict__ csr,
                                               float* __restrict__ AG) {
  int wid = threadIdx.x >> 6, lane = threadIdx.x & 63;
  int node = blockIdx.x * 4 + wid;
  if (node >= Nn) return;
  int q4 = lane >> 4;
  int cg = (lane & 15) * 8;
  float s[8] = {0.f, 0.f, 0.f, 0.f, 0.f, 0.f, 0.f, 0.f};
  int j0 = offs[node], j1 = offs[node + 1];
  for (int j = j0; j < j1; j += 8) {
    int e1 = j + q4, e2 = j + 4 + q4;
    int r1 = csr[min(e1, j1 - 1)];
    int r2 = csr[min(e2, j1 - 1)];
    float m1 = (e1 < j1) ? 1.f : 0.f;
    float m2 = (e2 < j1) ? 1.f : 0.f;
    short8 v1 = *(const short8*)(P + (size_t)r1 * 128 + cg);
    short8 v2 = *(const short8*)(P + (size_t)r2 * 128 + cg);
    #pragma unroll
    for (int q = 0; q < 8; q++) s[q] += m1 * bf2f((unsigned short)v1[q]);
    #pragma unroll
    for (int q = 0; q < 8; q++) s[q] += m2 * bf2f((unsigned short)v2[q]);
  }
  #pragma unroll
  for (int q = 0; q < 8; q++) {
    s[q] += __shfl_xor(s[q], 32);
    s[q] += __shfl_xor(s[q], 16);
  }
  if (q4 == 0) {
    float inv = 1.f / fmaxf((float)cnt[node], 1.f);
    float* dst = AG + (size_t)node * 128 + cg;
    *(float4*)dst = make_float4(s[0] * inv, s[1] * inv, s[2] * inv, s[3] * inv);
    *(float4*)(dst + 4) = make_float4(s[4] * inv, s[5] * inv, s[6] * inv, s[7] * inv);
  }
}

// ---------------- weight prep: W[K][N] fp32 -> bf16 [N][K] ----------------
__global__ void k_prep(const float* __restrict__ W, int K, int N,
                       unsigned short* __restrict__ Hi) {
  int idx = blockIdx.x * 256 + threadIdx.x;
  if (idx >= K * N) return;
  int k = idx / N, n = idx - k * N;
  Hi[(size_t)n * K + k] = f2bf_rtn(W[idx]);
}

__global__ void k_bias_pad(const float* __restrict__ b, float* __restrict__ out) {
  int i = threadIdx.x;
  out[i] = (i < 128) ? b[i] : 0.f;
}

// ---------------- bf16 MFMA GEMM, BM=64 BN=256 BK=32, dbuf + LDS epilogue, 4 blocks/CU ----------------
// LDS (40KB, ushort offsets): Ash[b] @ b*2048 (64x32=2048 each); Bsh[b] @ 4096 + b*8192 (256x32=8192 each)
template <int PASSES, bool RELU, bool SPLITOUT>
__global__ __launch_bounds__(256, 4) void k_gemm(
    const unsigned short* __restrict__ A1, const unsigned short* __restrict__ B1,
    const unsigned short* __restrict__ A2, const unsigned short* __restrict__ B2,
    const float* __restrict__ bias,
    unsigned short* __restrict__ Cb, float* __restrict__ S3, unsigned short* __restrict__ P3,
    int K) {
  __shared__ __align__(16) unsigned short smem[20480];   // 40KB
  const int tid = threadIdx.x;
  const int lane = tid & 63;
  const int wid = tid >> 6;
  const int l15 = lane & 15, l4 = lane >> 4;
  const int wm = (wid >> 1) * 32;        // wave row offset (0/32)
  const int wn2 = (wid & 1) * 128;       // wave col offset (0/128)
  const int row0 = blockIdx.x * 64;
  const int srow = lane >> 2;
  const int sg = ((lane & 3) ^ ((lane >> 3) & 3)) * 8;
  const int gsw = (l4 ^ ((l15 >> 1) & 3)) * 8;

  const int ktiles = K >> 5;
  const int nt = PASSES * ktiles;

  auto Ash = [&](int b) { return smem + b * 2048; };
  auto Bsh = [&](int b) { return smem + 4096 + b * 8192; };

  auto stage = [&](int t, int b) {
    int pass = (PASSES == 2 && t >= ktiles) ? 1 : 0;
    int k0 = (t - pass * ktiles) << 5;
    const unsigned short* gA = pass ? A2 : A1;
    const unsigned short* gB = pass ? B2 : B1;
    #pragma unroll
    for (int cc = 0; cc < 5; ++cc) {
      int c = wid * 5 + cc;
      unsigned short* lb;
      const unsigned short* gb;
      int grow;
      if (c < 4) { lb = Ash(b) + c * 512;              gb = gA; grow = row0 + c * 16 + srow; }
      else       { int q = c - 4; lb = Bsh(b) + q * 512; gb = gB; grow = q * 16 + srow; }
      __builtin_amdgcn_global_load_lds(
          (const __attribute__((address_space(1))) void*)(gb + (size_t)grow * K + k0 + sg),
          (__attribute__((address_space(3))) void*)lb, 16, 0, 0);
    }
  };

  f32x4 acc[2][8];
  #pragma unroll
  for (int s = 0; s < 2; ++s)
    #pragma unroll
    for (int t = 0; t < 8; ++t) acc[s][t] = (f32x4)0.0f;

  stage(0, 0);
  __syncthreads();
  for (int t = 0; t < nt; ++t) {
    int buf = t & 1;
    if (t + 1 < nt) stage(t + 1, buf ^ 1);
    short8 af[2];
    #pragma unroll
    for (int s = 0; s < 2; ++s)
      af[s] = *(const short8*)&Ash(buf)[(wm + s * 16 + l15) * 32 + gsw];
    #pragma unroll
    for (int tt = 0; tt < 8; ++tt) {
      short8 b = *(const short8*)&Bsh(buf)[(wn2 + tt * 16 + l15) * 32 + gsw];
      #pragma unroll
      for (int s = 0; s < 2; ++s)
        acc[s][tt] = __builtin_amdgcn_mfma_f32_16x16x32_bf16(af[s], b, acc[s][tt], 0, 0, 0);
    }
    __syncthreads();
  }

  // ---- epilogue: stage bf16 output in LDS, then coalesced short8 streams ----
  if (!SPLITOUT) {
    unsigned short* Cs = smem;   // 64x256 bf16 = 32KB
    #pragma unroll
    for (int tt = 0; tt < 8; ++tt) {
      int col = wn2 + tt * 16 + l15;
      float bv = bias[col];
      #pragma unroll
      for (int s = 0; s < 2; ++s) {
        int r = wm + s * 16 + l4 * 4;
        #pragma unroll
        for (int j = 0; j < 4; ++j) {
          float v = acc[s][tt][j] + bv;
          if (RELU) v = fmaxf(v, 0.f);
          Cs[(r + j) * 256 + col] = f2bf_rtn(v);
        }
      }
    }
    __syncthreads();
    #pragma unroll
    for (int it = 0; it < 8; ++it) {
      int ch = it * 256 + tid;
      int row = row0 + (ch >> 5);
      if (row < Nn)
        *(short8*)(Cb + (size_t)row * 256 + (ch & 31) * 8) = *(const short8*)&Cs[ch * 8];
    }
  } else {
    unsigned short* Ps = smem;   // 64x128 bf16 = 16KB
    #pragma unroll
    for (int tt = 0; tt < 8; ++tt) {
      int col = wn2 + tt * 16 + l15;
      float bv = bias[col];
      #pragma unroll
      for (int s = 0; s < 2; ++s) {
        int r = wm + s * 16 + l4 * 4;
        #pragma unroll
        for (int j = 0; j < 4; ++j) {
          float v = acc[s][tt][j] + bv;
          if (RELU) v = fmaxf(v, 0.f);
          int row = row0 + r + j;
          if (wn2 == 0) {
            if (row < Nn) S3[(size_t)row * 128 + col] = v;
          } else {
            Ps[(r + j) * 128 + (col - 128)] = f2bf_rtn(v);
          }
        }
      }
    }
    __syncthreads();
    #pragma unroll
    for (int it = 0; it < 4; ++it) {
      int ch = it * 256 + tid;
      int row = row0 + (ch >> 4);
      if (row < Nn)
        *(short8*)(P3 + (size_t)row * 128 + (ch & 15) * 8) = *(const short8*)&Ps[ch * 8];
    }
  }
}

// ---------------- final classifier: h3 = relu(S3 + AG3); out = h3 @ clw + clb ----------------
__global__ __launch_bounds__(256) void k_cls2(const float* __restrict__ S3,
                                              const float* __restrict__ AG3,
                                              const float* __restrict__ W,
                                              const float* __restrict__ B,
                                              float* __restrict__ out) {
  __shared__ float sw[1024];
  __shared__ float sb[8];
  for (int i = threadIdx.x; i < 1024; i += 256) sw[i] = W[i];
  if (threadIdx.x < 8) sb[threadIdx.x] = B[threadIdx.x];
  __syncthreads();
  int node = blockIdx.x * 256 + threadIdx.x;
  if (node >= Nn) return;
  float acc[8];
  #pragma unroll
  for (int o = 0; o < 8; o++) acc[o] = sb[o];
  const float4* s4 = (const float4*)(S3 + (size_t)node * 128);
  const float4* a4 = (const float4*)(AG3 + (size_t)node * 128);
  for (int k4 = 0; k4 < 32; k4++) {
    float4 sv = s4[k4];
    float4 av = a4[k4];
    float vv[4] = {fmaxf(sv.x + av.x, 0.f), fmaxf(sv.y + av.y, 0.f),
                   fmaxf(sv.z + av.z, 0.f), fmaxf(sv.w + av.w, 0.f)};
    #pragma unroll
    for (int j = 0; j < 4; j++) {
      int k = k4 * 4 + j;
      #pragma unroll
      for (int o = 0; o < 8; o++) acc[o] += vv[j] * sw[k * 8 + o];
    }
  }
  float4* orow = (float4*)(out + (size_t)node * 8);
  orow[0] = make_float4(acc[0], acc[1], acc[2], acc[3]);
  orow[1] = make_float4(acc[4], acc[5], acc[6], acc[7]);
}

extern "C" void kernel_launch(void* const* d_in, const int* in_sizes, int n_in,
                              void* d_out, int out_size, void* d_ws, size_t ws_size,
                              hipStream_t stream) {
  (void)in_sizes; (void)n_in; (void)out_size; (void)ws_size;
  const float* feat = (const float*)d_in[0];
  const int* eidx = (const int*)d_in[1];
  const int* esrc = eidx;
  const int* edst = eidx + Ee;
  const float* gw1 = (const float*)d_in[2];  const float* gb1 = (const float*)d_in[3];
  const float* gw2 = (const float*)d_in[4];  const float* gb2 = (const float*)d_in[5];
  const float* aw1 = (const float*)d_in[6];  const float* ab1 = (const float*)d_in[7];
  const float* aw2 = (const float*)d_in[8];  const float* ab2 = (const float*)d_in[9];
  const float* c1ws = (const float*)d_in[10]; const float* c1wn = (const float*)d_in[11]; const float* c1b = (const float*)d_in[12];
  const float* c2ws = (const float*)d_in[13]; const float* c2wn = (const float*)d_in[14]; const float* c2b = (const float*)d_in[15];
  const float* c3ws = (const float*)d_in[16]; const float* c3wn = (const float*)d_in[17]; const float* c3b = (const float*)d_in[18];
  const float* clw = (const float*)d_in[19];  const float* clb = (const float*)d_in[20];
  float* out = (float*)d_out;

  char* ws = (char*)d_ws;
  size_t off = 0;
  auto alloc = [&](size_t b) -> char* {
    char* p = ws + off;
    off = (off + b + 255) & ~(size_t)255;
    return p;
  };
  int* cnt = (int*)alloc(Nn * 4);
  int* cur = (int*)alloc(Nn * 4);
  double* accF = (double*)alloc(128 * 8);
  double* accR = (double*)alloc(128 * 8);
  double* accZ = (double*)alloc(128 * 8);
  size_t zbytes = off;  // region above must be zeroed
  int* offs = (int*)alloc((size_t)(Nn + 1) * 4);
  int* csr = (int*)alloc((size_t)Ee * 4);
  int* bsum = (int*)alloc(NBLK * 4);
  int* bbase = (int*)alloc(NBLK * 4);
  float* dinv = (float*)alloc(Nn * 4);
  unsigned short* B1s = (unsigned short*)alloc(256 * 64 * 2);
  unsigned short* B1n = (unsigned short*)alloc(256 * 64 * 2);
  unsigned short* B2s = (unsigned short*)alloc(256 * 256 * 2);
  unsigned short* B2n = (unsigned short*)alloc(256 * 256 * 2);
  unsigned short* B3 = (unsigned short*)alloc(256 * 256 * 2);
  float* b3p = (float*)alloc(256 * 4);
  float* Xs = (float*)alloc((size_t)Nn * 64 * 4);
  float* Zf = (float*)alloc((size_t)Nn * 64 * 4);
  unsigned short* H0h = (unsigned short*)alloc((size_t)Nn * 64 * 2);
  unsigned short* AG0 = (unsigned short*)alloc((size_t)Nn * 64 * 2);
  unsigned short* H1h = (unsigned short*)alloc((size_t)Nn * 256 * 2);
  unsigned short* AG1 = (unsigned short*)alloc((size_t)Nn * 256 * 2);
  unsigned short* H2h = (unsigned short*)alloc((size_t)Nn * 256 * 2);
  alloc(65536);  // guard for OOB A-row staging
  float* S3f = (float*)Zf;            // alias (Zf dead after k_attn)
  unsigned short* P3h = AG1;          // alias (AG1 dead after GEMM2)
  float* AG3 = (float*)H1h;           // alias (H1 dead after GEMM2)

  hipMemsetAsync(d_ws, 0, zbytes, stream);

  hipLaunchKernelGGL(k_prep, dim3(64), dim3(256), 0, stream, c1ws, 64, 256, B1s);
  hipLaunchKernelGGL(k_prep, dim3(64), dim3(256), 0, stream, c1wn, 64, 256, B1n);
  hipLaunchKernelGGL(k_prep, dim3(256), dim3(256), 0, stream, c2ws, 256, 256, B2s);
  hipLaunchKernelGGL(k_prep, dim3(256), dim3(256), 0, stream, c2wn, 256, 256, B2n);
  hipLaunchKernelGGL(k_prep, dim3(128), dim3(256), 0, stream, c3ws, 256, 128, B3);
  hipLaunchKernelGGL(k_prep, dim3(128), dim3(256), 0, stream, c3wn, 256, 128, B3 + 128 * 256);
  hipLaunchKernelGGL(k_bias_pad, dim3(1), dim3(256), 0, stream, c3b, b3p);

  int eb = (Ee + 255) / 256;
  hipLaunchKernelGGL(k_count, dim3(eb), dim3(256), 0, stream, edst, cnt);
  hipLaunchKernelGGL(k_bsum, dim3(NBLK), dim3(256), 0, stream, cnt, bsum);
  hipLaunchKernelGGL(k_bscan, dim3(1), dim3(256), 0, stream, bsum, bbase, offs);
  hipLaunchKernelGGL(k_offsets, dim3(NBLK), dim3(256), 0, stream, cnt, bbase, offs, dinv);
  hipLaunchKernelGGL(k_scatter, dim3(eb), dim3(256), 0, stream, esrc, edst, offs, cur, csr);

  hipLaunchKernelGGL((k_stats<true>), dim3(196), dim3(256), 0, stream, feat, accF, dinv, Xs);

  hipLaunchKernelGGL(k_energy, dim3((Nn + 3) / 4), dim3(256), 0, stream,
                     Xs, cnt, offs, csr, Zf);
  hipLaunchKernelGGL((k_stats<false>), dim3(196), dim3(256), 0, stream, Zf, accR,
                     (const float*)nullptr, (float*)nullptr);

  hipLaunchKernelGGL(k_gate, dim3((Nn + 255) / 256), dim3(256), 0, stream,
                     feat, accF, accR, gw1, gb1, gw2, gb2, Zf);
  hipLaunchKernelGGL((k_stats<false>), dim3(196), dim3(256), 0, stream, Zf, accZ,
                     (const float*)nullptr, (float*)nullptr);

  hipLaunchKernelGGL(k_attn, dim3(196), dim3(256), 0, stream,
                     accZ, aw1, ab1, aw2, ab2, Zf, H0h);

  hipLaunchKernelGGL(k_pull64b, dim3((Nn + 3) / 4), dim3(256), 0, stream,
                     H0h, cnt, offs, csr, AG0);
  hipLaunchKernelGGL((k_gemm<2, true, false>), dim3(782), dim3(256), 0, stream,
                     H0h, B1s, AG0, B1n, c1b,
                     H1h, (float*)nullptr, (unsigned short*)nullptr, 64);
  hipLaunchKernelGGL(k_pull256b, dim3((Nn + 3) / 4), dim3(256), 0, stream,
                     H1h, cnt, offs, csr, AG1);
  hipLaunchKernelGGL((k_gemm<2, true, false>), dim3(782), dim3(256), 0, stream,
                     H1h, B2s, AG1, B2n, c2b,
                     H2h, (float*)nullptr, (unsigned short*)nullptr, 256);
  hipLaunchKernelGGL((k_gemm<1, false, true>), dim3(782), dim3(256), 0, stream,
                     H2h, B3, (const unsigned short*)nullptr, (const unsigned short*)nullptr,
                     b3p, (unsigned short*)nullptr, S3f, P3h, 256);
  hipLaunchKernelGGL(k_pullh, dim3((Nn + 3) / 4), dim3(256), 0, stream,
                     P3h, cnt, offs, csr, AG3);
  hipLaunchKernelGGL(k_cls2, dim3((Nn + 255) / 256), dim3(256), 0, stream,
                     S3f, AG3, clw, clb, out);
}